// Round 1
// baseline (173.713 us; speedup 1.0000x reference)
//
#include <hip/hip_runtime.h>
#include <hip/hip_bf16.h>

#define H_ 8
#define D_ 64
#define IN_ 512
#define B_ 4
#define N_ 2048
#define TOK_ (B_*N_)
// softmax in exp2 domain: scale * log2(e) (folded into Q at projection time)
#define CLOG2_ 0.18033688011112042f

typedef __attribute__((ext_vector_type(8))) short short8;
typedef __attribute__((ext_vector_type(4))) short bs4;
typedef __attribute__((ext_vector_type(4))) float f32x4;

__device__ __forceinline__ unsigned short f2bf(float f) {
  unsigned int u = __float_as_uint(f);
  u += 0x7FFFu + ((u >> 16) & 1u);
  return (unsigned short)(u >> 16);
}

// packed converts: v_cvt_pk_bf16_f32
__device__ __forceinline__ short8 cvt8(const float4 a, const float4 b) {
  union { short8 v; __hip_bfloat162 h[4]; } z;
  z.h[0] = __float22bfloat162_rn(make_float2(a.x, a.y));
  z.h[1] = __float22bfloat162_rn(make_float2(a.z, a.w));
  z.h[2] = __float22bfloat162_rn(make_float2(b.x, b.y));
  z.h[3] = __float22bfloat162_rn(make_float2(b.z, b.w));
  return z.v;
}

__device__ __forceinline__ bs4 pack4(float a, float b, float c, float d) {
  union { bs4 v; __hip_bfloat162 h[2]; } z;
  z.h[0] = __float22bfloat162_rn(make_float2(a, b));
  z.h[1] = __float22bfloat162_rn(make_float2(c, d));
  return z.v;
}

// async global->LDS, 16B per lane; dest = wave-uniform base + lane*16
__device__ __forceinline__ void gld16(const unsigned short* g, unsigned short* l) {
  __builtin_amdgcn_global_load_lds(
      (const __attribute__((address_space(1))) void*)g,
      (__attribute__((address_space(3))) void*)l, 16, 0, 0);
}

// ---------------------------------------------------------------------------
// Kernel 0: merged fp32 -> bf16 convert (x, Wq, Wkv, Wo) in ONE launch.
// Each block converts 2048 elements.
// ---------------------------------------------------------------------------
__global__ __launch_bounds__(256) void conv_all_kernel(
    const float* __restrict__ x, const float* __restrict__ Wq,
    const float* __restrict__ Wkv, const float* __restrict__ Wo,
    unsigned short* __restrict__ xbf, unsigned short* __restrict__ wbf,
    unsigned short* __restrict__ wobf)
{
  const int b = blockIdx.x;
  const float* src;
  unsigned short* dst;
  size_t base;
  if (b < 2048)      { src = x;   dst = xbf;             base = (size_t)b * 2048; }
  else if (b < 2176) { src = Wq;  dst = wbf;             base = (size_t)(b - 2048) * 2048; }
  else if (b < 2432) { src = Wkv; dst = wbf + 512 * 512; base = (size_t)(b - 2176) * 2048; }
  else               { src = Wo;  dst = wobf;            base = (size_t)(b - 2432) * 2048; }
  size_t i = base + (size_t)threadIdx.x * 8;
  float4 a = *(const float4*)(src + i);
  float4 c = *(const float4*)(src + i + 4);
  *(short8*)(dst + i) = cvt8(a, c);
}

// ---------------------------------------------------------------------------
// Kernel 1: QKV projection. 128x128 tile, BK=32, DOUBLE-BUFFERED
// global_load_lds staging (one barrier/iter — loads for tile k+1 fly under
// compute of tile k), source-permuted XOR swizzle (granule (tid&3)^(row&3)).
// Q pre-scaled by CLOG2_. Q,K -> [b,h,n,d]; V -> [b,h,d,n]. LDS epilogues.
// XCD-chunked block swizzle (T1): 96 consecutive ids per XCD, col-tile
// fastest-varying -> per-XCD working set = 8 A-panels + all 12 B-panels
// (~2.5 MB, L2-fit; weights fully reused per XCD). 768 % 8 == 0 (bijective).
// ---------------------------------------------------------------------------
__global__ __launch_bounds__(256) void qkv_gemm_kernel(
    const unsigned short* __restrict__ xbf, const unsigned short* __restrict__ wbf,
    unsigned short* __restrict__ qws, unsigned short* __restrict__ kws,
    unsigned short* __restrict__ vws)
{
  // staging: buf b at sm + b*8192 (A 4096 | B 4096 shorts); epilogue overlay 128*136
  __shared__ __attribute__((aligned(16))) unsigned short sm[128 * 136];

  const int lid = blockIdx.x + (blockIdx.y << 6);      // grid (64,12), 0..767
  const int swz = (lid & 7) * 96 + (lid >> 3);         // bijective XCD chunking
  const int t0 = (swz / 12) * 128;
  const int c0 = (swz % 12) * 128;                     // 0..1535 over [Wq|Wkv] rows
  const int cls = c0 >> 9;                             // 0=q 1=k 2=v

  const int tid = threadIdx.x;
  const int wave = tid >> 6, lane = tid & 63;
  const int quad = lane >> 4, l16 = lane & 15;
  const int wm = wave >> 1, wn = wave & 1;

  // staging source: row r = i*64 + tid>>2, granule gc = (tid&3)^(r&3)
  const int r_ = tid >> 2;
  const int gc = (tid & 3) ^ (r_ & 3);
  const unsigned short* abase = xbf + (size_t)(t0 + r_) * IN_ + gc * 8;
  const unsigned short* bbase = wbf + (size_t)(c0 + r_) * IN_ + gc * 8;

  auto stage = [&](int k0, int buf) {
    unsigned short* sA = sm + buf * 8192;
    unsigned short* sB = sA + 4096;
    gld16(abase + k0,            sA + tid * 8);
    gld16(abase + 64 * IN_ + k0, sA + 2048 + tid * 8);
    gld16(bbase + k0,            sB + tid * 8);
    gld16(bbase + 64 * IN_ + k0, sB + 2048 + tid * 8);
  };

  f32x4 acc[4][4];
  #pragma unroll
  for (int i = 0; i < 4; i++)
    #pragma unroll
    for (int j = 0; j < 4; j++) acc[i][j] = (f32x4){0.f, 0.f, 0.f, 0.f};

  stage(0, 0);

  for (int kt = 0; kt < 16; kt++) {
    const int cur = kt & 1;
    __syncthreads();                       // tile kt landed; prev compute done
    if (kt + 1 < 16) stage((kt + 1) * 32, cur ^ 1);
    const unsigned short* sA = sm + cur * 8192;
    const unsigned short* sB = sA + 4096;
    const int sw = ((quad ^ (l16 & 3)) << 3);
    short8 af[4], bf[4];
    #pragma unroll
    for (int mi = 0; mi < 4; mi++)
      af[mi] = *(const short8*)&sA[(wm * 64 + mi * 16 + l16) * 32 + sw];
    #pragma unroll
    for (int ni = 0; ni < 4; ni++)
      bf[ni] = *(const short8*)&sB[(wn * 64 + ni * 16 + l16) * 32 + sw];
    #pragma unroll
    for (int mi = 0; mi < 4; mi++)
      #pragma unroll
      for (int ni = 0; ni < 4; ni++)
        acc[mi][ni] = __builtin_amdgcn_mfma_f32_16x16x32_bf16(af[mi], bf[ni], acc[mi][ni], 0, 0, 0);
  }

  __syncthreads();  // main-loop LDS reads done; reuse sm for epilogue

  if (cls < 2) {
    // token-major C tile [128 tok][136], coalesced 128B-run readback
    const float qs = (cls == 0) ? CLOG2_ : 1.0f;   // fold softmax scale into Q
    #pragma unroll
    for (int mi = 0; mi < 4; mi++) {
      const int row0 = wm * 64 + mi * 16 + quad * 4;
      #pragma unroll
      for (int ni = 0; ni < 4; ni++) {
        const int col = wn * 64 + ni * 16 + l16;
        #pragma unroll
        for (int r = 0; r < 4; r++)
          sm[(row0 + r) * 136 + col] = f2bf(acc[mi][ni][r] * qs);
      }
    }
    __syncthreads();
    const int row = tid >> 1, half = tid & 1;
    const int t = t0 + row, bb = t >> 11, nn = t & (N_ - 1);
    const int cw = (c0 & 511) + half * 64;
    const int hh = cw >> 6;
    unsigned short* dst = ((cls == 0) ? qws : kws) +
                          ((size_t)(bb * H_ + hh) * N_ + nn) * D_;
    const unsigned short* srcp = &sm[row * 136 + half * 64];
    #pragma unroll
    for (int j = 0; j < 8; j++)
      *(uint4*)(dst + j * 8) = *(const uint4*)(srcp + j * 8);
  } else {
    // transposed C tile [128 col][136 tok], coalesced readback along n
    #pragma unroll
    for (int mi = 0; mi < 4; mi++) {
      const int tk = wm * 64 + mi * 16 + quad * 4;
      #pragma unroll
      for (int ni = 0; ni < 4; ni++) {
        const int col = wn * 64 + ni * 16 + l16;
        bs4 pk4 = pack4(acc[mi][ni][0], acc[mi][ni][1], acc[mi][ni][2], acc[mi][ni][3]);
        *(bs4*)&sm[col * 136 + tk] = pk4;
      }
    }
    __syncthreads();
    const int col = tid >> 1, half = tid & 1;
    const int cw = (c0 - 1024) + col;
    const int hh = cw >> 6, dd = cw & 63;
    const int bb = t0 >> 11, n0 = (t0 & (N_ - 1)) + half * 64;
    unsigned short* dst = vws + ((size_t)(bb * H_ + hh) * D_ + dd) * N_ + n0;
    const unsigned short* srcp = &sm[col * 136 + half * 64];
    #pragma unroll
    for (int j = 0; j < 8; j++)
      *(uint4*)(dst + j * 8) = *(const uint4*)(srcp + j * 8);
  }
}

// ---------------------------------------------------------------------------
// Kernel 2: flash attention. Transposed-S, unshifted exp2 (scale pre-folded
// into Q), q-tile 64, ones-MFMA l accumulation, global_load_lds dbuf staging,
// 1 barrier/iter.
// XCD-chunked block swizzle (T1): each XCD owns 4 contiguous bh (128
// consecutive ids) -> per-XCD K/V working set 4 x 512 KB = 2 MB < 4 MB L2.
// Fixes the measured 2.8x K/V over-fetch (69.7 MB vs ~25 MB ideal): with
// default round-robin dispatch each XCD saw all 32 bh (16 MB) and thrashed.
// 1024 % 8 == 0 (bijective).
// ---------------------------------------------------------------------------
__global__ __launch_bounds__(256) void attention_kernel(
    const unsigned short* __restrict__ qws,
    const unsigned short* __restrict__ kws,
    const unsigned short* __restrict__ vws,
    unsigned short* __restrict__ ows)
{
  __shared__ __attribute__((aligned(16))) unsigned short sm[2][8192];

  const int lid = blockIdx.x + (blockIdx.y << 5);      // grid (32,32), 0..1023
  const int swz = ((lid & 7) << 7) + (lid >> 3);       // bijective XCD chunking
  const int q0 = (swz & 31) * 64;                      // q-tile fast within chunk
  const int bh = swz >> 5;                             // 4 contiguous bh per XCD
  const int tid = threadIdx.x;
  const int wave = tid >> 6, lane = tid & 63;
  const int quad = lane >> 4, l16 = lane & 15;

  const unsigned short* qbase = qws + (size_t)bh * N_ * D_;
  const unsigned short* kbase = kws + (size_t)bh * N_ * D_;
  const unsigned short* vbase = vws + (size_t)bh * D_ * N_;

  const int qrow = q0 + wave * 16 + l16;
  short8 qf[2];
  #pragma unroll
  for (int kc = 0; kc < 2; kc++)
    qf[kc] = *(const short8*)(qbase + (size_t)qrow * D_ + kc * 32 + quad * 8);

  f32x4 ot[4];
  f32x4 otl;
  #pragma unroll
  for (int db = 0; db < 4; db++) ot[db] = (f32x4){0.f, 0.f, 0.f, 0.f};
  otl = (f32x4){0.f, 0.f, 0.f, 0.f};
  const bs4 ones4 = {(short)0x3F80, (short)0x3F80, (short)0x3F80, (short)0x3F80};

  const int r_ = tid >> 3;
  const int gc = (tid & 7) ^ (r_ & 7);
  const unsigned short* kst = kbase + (size_t)r_ * D_ + gc * 8;
  const unsigned short* vst = vbase + (size_t)r_ * N_ + gc * 8;

  {
    unsigned short* Ks = &sm[0][0];
    unsigned short* Vs = &sm[0][4096];
    gld16(kst,                 Ks + tid * 8);
    gld16(kst + 32 * D_,       Ks + 2048 + tid * 8);
    gld16(vst,                 Vs + tid * 8);
    gld16(vst + 32 * N_,       Vs + 2048 + tid * 8);
  }

  for (int kt = 0; kt < N_ / 64; kt++) {
    const int cur = kt & 1;
    __syncthreads();
    if (kt + 1 < N_ / 64) {
      const int k0 = (kt + 1) * 64;
      unsigned short* Ks = &sm[cur ^ 1][0];
      unsigned short* Vs = &sm[cur ^ 1][4096];
      gld16(kst + (size_t)k0 * D_,            Ks + tid * 8);
      gld16(kst + (size_t)(k0 + 32) * D_,     Ks + 2048 + tid * 8);
      gld16(vst + k0,                         Vs + tid * 8);
      gld16(vst + k0 + 32 * N_,               Vs + 2048 + tid * 8);
    }
    const unsigned short* Ks = &sm[cur][0];
    const unsigned short* Vs = &sm[cur][4096];

    f32x4 st[4];
    #pragma unroll
    for (int nb = 0; nb < 4; nb++) st[nb] = (f32x4){0.f, 0.f, 0.f, 0.f};
    #pragma unroll
    for (int kc = 0; kc < 2; kc++) {
      const int sw = (((kc * 4 + quad) ^ (l16 & 7)) << 3);
      #pragma unroll
      for (int nb = 0; nb < 4; nb++) {
        short8 kf = *(const short8*)&Ks[(nb * 16 + l16) * 64 + sw];
        st[nb] = __builtin_amdgcn_mfma_f32_16x16x32_bf16(kf, qf[kc], st[nb], 0, 0, 0);
      }
    }

    bs4 pf[4];
    #pragma unroll
    for (int nb = 0; nb < 4; nb++) {
      float p0 = __builtin_amdgcn_exp2f(st[nb][0]);
      float p1 = __builtin_amdgcn_exp2f(st[nb][1]);
      float p2 = __builtin_amdgcn_exp2f(st[nb][2]);
      float p3 = __builtin_amdgcn_exp2f(st[nb][3]);
      pf[nb] = pack4(p0, p1, p2, p3);
    }

    #pragma unroll
    for (int kb = 0; kb < 4; kb++) {
      const int g = kb * 2 + (quad >> 1);
      const int sub = (quad & 1) * 4;
      bs4 vf[4];
      #pragma unroll
      for (int db = 0; db < 4; db++)
        vf[db] = *(const bs4*)&Vs[(db * 16 + l16) * 64 + ((g ^ (l16 & 7)) << 3) + sub];
      #pragma unroll
      for (int db = 0; db < 4; db++)
        ot[db] = __builtin_amdgcn_mfma_f32_16x16x16bf16_1k(vf[db], pf[kb], ot[db], 0, 0, 0);
      otl = __builtin_amdgcn_mfma_f32_16x16x16bf16_1k(ones4, pf[kb], otl, 0, 0, 0);
    }
  }

  const float inv = 1.f / otl[0];
  __syncthreads();
  unsigned short* Os = (unsigned short*)sm;   // 64 x 72 overlay
  #pragma unroll
  for (int db = 0; db < 4; db++) {
    bs4 pk4 = pack4(ot[db][0] * inv, ot[db][1] * inv, ot[db][2] * inv, ot[db][3] * inv);
    *(bs4*)&Os[(wave * 16 + l16) * 72 + db * 16 + quad * 4] = pk4;
  }
  __syncthreads();
  const int b_ = bh >> 3, h_ = bh & 7;
  const int qloc = tid >> 2, chunk = tid & 3;
  unsigned short* dst = ows + ((size_t)b_ * N_ + q0 + qloc) * (H_ * D_) + h_ * 64 + chunk * 16;
  const unsigned short* srcp = &Os[qloc * 72 + chunk * 16];
  *(uint4*)dst = *(const uint4*)srcp;
  *(uint4*)(dst + 8) = *(const uint4*)(srcp + 8);
}

// ---------------------------------------------------------------------------
// Kernel 3: output projection. 128x64 tile, BK=32, DOUBLE-BUFFERED
// global_load_lds staging (one barrier/iter). fp32 out + bias, 64B-run stores.
// XCD-chunked block swizzle (T1): 64 consecutive ids per XCD, col-tile
// fastest -> per-XCD working set = 8 A-panels + full Wo (~1.5 MB, L2-fit).
// 512 % 8 == 0 (bijective).
// ---------------------------------------------------------------------------
__global__ __launch_bounds__(256) void out_gemm_kernel(
    const unsigned short* __restrict__ ain, const unsigned short* __restrict__ wobf,
    const float* __restrict__ bo, float* __restrict__ y)
{
  // buf b at sm + b*6144: A 4096 | B 2048 shorts; total 12288 shorts = 24 KB
  __shared__ __attribute__((aligned(16))) unsigned short sm[12288];

  const int lid = blockIdx.x + (blockIdx.y << 6);      // grid (64,8), 0..511
  const int swz = ((lid & 7) << 6) + (lid >> 3);       // bijective XCD chunking
  const int t0 = (swz >> 3) * 128;
  const int c0 = (swz & 7) * 64;
  const int tid = threadIdx.x;
  const int wave = tid >> 6, lane = tid & 63;
  const int quad = lane >> 4, l16 = lane & 15;

  const int r_ = tid >> 2;
  const int gc = (tid & 3) ^ (r_ & 3);
  const unsigned short* abase = ain  + (size_t)(t0 + r_) * IN_ + gc * 8;
  const unsigned short* bbase = wobf + (size_t)(c0 + r_) * IN_ + gc * 8;

  auto stage = [&](int k0, int buf) {
    unsigned short* sA = sm + buf * 6144;
    unsigned short* sB = sA + 4096;
    gld16(abase + k0,            sA + tid * 8);
    gld16(abase + 64 * IN_ + k0, sA + 2048 + tid * 8);
    gld16(bbase + k0,            sB + tid * 8);     // B: 64 rows x 4 granules = 256 slots
  };

  f32x4 acc[2][4];
  #pragma unroll
  for (int i = 0; i < 2; i++)
    #pragma unroll
    for (int j = 0; j < 4; j++) acc[i][j] = (f32x4){0.f, 0.f, 0.f, 0.f};

  stage(0, 0);

  for (int kt = 0; kt < 16; kt++) {
    const int cur = kt & 1;
    __syncthreads();
    if (kt + 1 < 16) stage((kt + 1) * 32, cur ^ 1);
    const unsigned short* sA = sm + cur * 6144;
    const unsigned short* sB = sA + 4096;
    const int sw = ((quad ^ (l16 & 3)) << 3);
    short8 af[2], bf[4];
    #pragma unroll
    for (int mi = 0; mi < 2; mi++)
      af[mi] = *(const short8*)&sA[(wave * 32 + mi * 16 + l16) * 32 + sw];
    #pragma unroll
    for (int ni = 0; ni < 4; ni++)
      bf[ni] = *(const short8*)&sB[(ni * 16 + l16) * 32 + sw];
    #pragma unroll
    for (int mi = 0; mi < 2; mi++)
      #pragma unroll
      for (int ni = 0; ni < 4; ni++)
        acc[mi][ni] = __builtin_amdgcn_mfma_f32_16x16x32_bf16(af[mi], bf[ni], acc[mi][ni], 0, 0, 0);
  }

  #pragma unroll
  for (int mi = 0; mi < 2; mi++) {
    const int t = t0 + wave * 32 + mi * 16 + quad * 4;
    #pragma unroll
    for (int ni = 0; ni < 4; ni++) {
      const int c = c0 + ni * 16 + l16;
      const float bias = bo[c];
      float* dst = y + (size_t)t * IN_ + c;
      dst[0]        = acc[mi][ni][0] + bias;
      dst[IN_]      = acc[mi][ni][1] + bias;
      dst[2 * IN_]  = acc[mi][ni][2] + bias;
      dst[3 * IN_]  = acc[mi][ni][3] + bias;
    }
  }
}

extern "C" void kernel_launch(void* const* d_in, const int* in_sizes, int n_in,
                              void* d_out, int out_size, void* d_ws, size_t ws_size,
                              hipStream_t stream) {
  const float* x   = (const float*)d_in[0];
  const float* Wq  = (const float*)d_in[1];
  const float* Wkv = (const float*)d_in[2];
  const float* Wo  = (const float*)d_in[3];
  const float* bo  = (const float*)d_in[4];
  float* out = (float*)d_out;

  // ws (shorts): qws 4M | kws 4M | vws 4M | ows 4M | wbf 768K | wobf 256K  (~34 MB, proven)
  unsigned short* qws  = (unsigned short*)d_ws;
  unsigned short* kws  = qws + (size_t)TOK_ * 512;
  unsigned short* vws  = kws + (size_t)TOK_ * 512;
  unsigned short* ows  = vws + (size_t)TOK_ * 512;
  unsigned short* wbf  = ows + (size_t)TOK_ * 512;       // [Wq 512 | Wkv 1024] x 512
  unsigned short* wobf = wbf + (size_t)1536 * 512;
  unsigned short* xbf  = ows;  // alias: consumed by qkv before attention writes ows

  conv_all_kernel<<<dim3(2560), 256, 0, stream>>>(x, Wq, Wkv, Wo, xbf, wbf, wobf);
  qkv_gemm_kernel<<<dim3(TOK_ / 128, 1536 / 128), 256, 0, stream>>>(xbf, wbf, qws, kws, vws);
  attention_kernel<<<dim3(N_ / 64, B_ * H_), 256, 0, stream>>>(qws, kws, vws, ows);
  out_gemm_kernel<<<dim3(TOK_ / 128, 512 / 64), 256, 0, stream>>>(ows, wobf, bo, out);
}

// Round 2
// 165.528 us; speedup vs baseline: 1.0494x; 1.0494x over previous
//
#include <hip/hip_runtime.h>
#include <hip/hip_bf16.h>

#define H_ 8
#define D_ 64
#define IN_ 512
#define B_ 4
#define N_ 2048
#define TOK_ (B_*N_)
// softmax in exp2 domain: scale * log2(e) (folded into Q at projection time)
#define CLOG2_ 0.18033688011112042f

typedef __attribute__((ext_vector_type(8))) short short8;
typedef __attribute__((ext_vector_type(4))) short bs4;
typedef __attribute__((ext_vector_type(4))) float f32x4;

__device__ __forceinline__ unsigned short f2bf(float f) {
  unsigned int u = __float_as_uint(f);
  u += 0x7FFFu + ((u >> 16) & 1u);
  return (unsigned short)(u >> 16);
}

// packed converts: v_cvt_pk_bf16_f32
__device__ __forceinline__ short8 cvt8(const float4 a, const float4 b) {
  union { short8 v; __hip_bfloat162 h[4]; } z;
  z.h[0] = __float22bfloat162_rn(make_float2(a.x, a.y));
  z.h[1] = __float22bfloat162_rn(make_float2(a.z, a.w));
  z.h[2] = __float22bfloat162_rn(make_float2(b.x, b.y));
  z.h[3] = __float22bfloat162_rn(make_float2(b.z, b.w));
  return z.v;
}

__device__ __forceinline__ bs4 pack4(float a, float b, float c, float d) {
  union { bs4 v; __hip_bfloat162 h[2]; } z;
  z.h[0] = __float22bfloat162_rn(make_float2(a, b));
  z.h[1] = __float22bfloat162_rn(make_float2(c, d));
  return z.v;
}

// Reassemble two K=16 P-fragments (keys nb*16+quad*4+r layout) into one K=32
// B-fragment (keys quad*8+j layout) with 4 lane-swaps. Derivation:
//   dword0/1 (j=0..3) come from src quad (2q')&3, dword2/3 (j=4..7) from
//   (2q'+1)&3, with nb = q'>>1. permlane32_swap then permlane16_swap puts
//   {x(q0),x(q2),y(q0),y(q2)} in out[0] and {x(q1),x(q3),y(q1),y(q3)} in
//   out[1] — exactly the needed quad relabeling.
__device__ __forceinline__ short8 assemble_p(bs4 pa, bs4 pb) {
  union { bs4 v; unsigned int w[2]; } A, B;
  A.v = pa; B.v = pb;
  auto s0 = __builtin_amdgcn_permlane32_swap(A.w[0], B.w[0], false, false);
  auto s1 = __builtin_amdgcn_permlane32_swap(A.w[1], B.w[1], false, false);
  auto t0 = __builtin_amdgcn_permlane16_swap(s0[0], s0[1], false, false);
  auto t1 = __builtin_amdgcn_permlane16_swap(s1[0], s1[1], false, false);
  union { short8 v; unsigned int w[4]; } R;
  R.w[0] = t0[0];   // j=0,1
  R.w[1] = t1[0];   // j=2,3
  R.w[2] = t0[1];   // j=4,5
  R.w[3] = t1[1];   // j=6,7
  return R.v;
}

// async global->LDS, 16B per lane; dest = wave-uniform base + lane*16
__device__ __forceinline__ void gld16(const unsigned short* g, unsigned short* l) {
  __builtin_amdgcn_global_load_lds(
      (const __attribute__((address_space(1))) void*)g,
      (__attribute__((address_space(3))) void*)l, 16, 0, 0);
}

// ---------------------------------------------------------------------------
// Kernel 0: merged fp32 -> bf16 convert (x, Wq, Wkv, Wo) in ONE launch.
// Each block converts 2048 elements.
// ---------------------------------------------------------------------------
__global__ __launch_bounds__(256) void conv_all_kernel(
    const float* __restrict__ x, const float* __restrict__ Wq,
    const float* __restrict__ Wkv, const float* __restrict__ Wo,
    unsigned short* __restrict__ xbf, unsigned short* __restrict__ wbf,
    unsigned short* __restrict__ wobf)
{
  const int b = blockIdx.x;
  const float* src;
  unsigned short* dst;
  size_t base;
  if (b < 2048)      { src = x;   dst = xbf;             base = (size_t)b * 2048; }
  else if (b < 2176) { src = Wq;  dst = wbf;             base = (size_t)(b - 2048) * 2048; }
  else if (b < 2432) { src = Wkv; dst = wbf + 512 * 512; base = (size_t)(b - 2176) * 2048; }
  else               { src = Wo;  dst = wobf;            base = (size_t)(b - 2432) * 2048; }
  size_t i = base + (size_t)threadIdx.x * 8;
  float4 a = *(const float4*)(src + i);
  float4 c = *(const float4*)(src + i + 4);
  *(short8*)(dst + i) = cvt8(a, c);
}

// ---------------------------------------------------------------------------
// Kernel 1: QKV projection. 128x128 tile, BK=32, DOUBLE-BUFFERED
// global_load_lds staging (one barrier/iter — loads for tile k+1 fly under
// compute of tile k), source-permuted XOR swizzle (granule (tid&3)^(row&3)).
// Q pre-scaled by CLOG2_. Q,K -> [b,h,n,d]; V -> [b,h,d,n]. LDS epilogues.
// XCD-chunked block swizzle (T1, bijective: 768%8==0).
// ---------------------------------------------------------------------------
__global__ __launch_bounds__(256) void qkv_gemm_kernel(
    const unsigned short* __restrict__ xbf, const unsigned short* __restrict__ wbf,
    unsigned short* __restrict__ qws, unsigned short* __restrict__ kws,
    unsigned short* __restrict__ vws)
{
  // staging: buf b at sm + b*8192 (A 4096 | B 4096 shorts); epilogue overlay 128*136
  __shared__ __attribute__((aligned(16))) unsigned short sm[128 * 136];

  const int lid = blockIdx.x + (blockIdx.y << 6);      // grid (64,12), 0..767
  const int swz = (lid & 7) * 96 + (lid >> 3);         // bijective XCD chunking
  const int t0 = (swz / 12) * 128;
  const int c0 = (swz % 12) * 128;                     // 0..1535 over [Wq|Wkv] rows
  const int cls = c0 >> 9;                             // 0=q 1=k 2=v

  const int tid = threadIdx.x;
  const int wave = tid >> 6, lane = tid & 63;
  const int quad = lane >> 4, l16 = lane & 15;
  const int wm = wave >> 1, wn = wave & 1;

  // staging source: row r = i*64 + tid>>2, granule gc = (tid&3)^(r&3)
  const int r_ = tid >> 2;
  const int gc = (tid & 3) ^ (r_ & 3);
  const unsigned short* abase = xbf + (size_t)(t0 + r_) * IN_ + gc * 8;
  const unsigned short* bbase = wbf + (size_t)(c0 + r_) * IN_ + gc * 8;

  auto stage = [&](int k0, int buf) {
    unsigned short* sA = sm + buf * 8192;
    unsigned short* sB = sA + 4096;
    gld16(abase + k0,            sA + tid * 8);
    gld16(abase + 64 * IN_ + k0, sA + 2048 + tid * 8);
    gld16(bbase + k0,            sB + tid * 8);
    gld16(bbase + 64 * IN_ + k0, sB + 2048 + tid * 8);
  };

  f32x4 acc[4][4];
  #pragma unroll
  for (int i = 0; i < 4; i++)
    #pragma unroll
    for (int j = 0; j < 4; j++) acc[i][j] = (f32x4){0.f, 0.f, 0.f, 0.f};

  stage(0, 0);

  for (int kt = 0; kt < 16; kt++) {
    const int cur = kt & 1;
    __syncthreads();                       // tile kt landed; prev compute done
    if (kt + 1 < 16) stage((kt + 1) * 32, cur ^ 1);
    const unsigned short* sA = sm + cur * 8192;
    const unsigned short* sB = sA + 4096;
    const int sw = ((quad ^ (l16 & 3)) << 3);
    short8 af[4], bf[4];
    #pragma unroll
    for (int mi = 0; mi < 4; mi++)
      af[mi] = *(const short8*)&sA[(wm * 64 + mi * 16 + l16) * 32 + sw];
    #pragma unroll
    for (int ni = 0; ni < 4; ni++)
      bf[ni] = *(const short8*)&sB[(wn * 64 + ni * 16 + l16) * 32 + sw];
    #pragma unroll
    for (int mi = 0; mi < 4; mi++)
      #pragma unroll
      for (int ni = 0; ni < 4; ni++)
        acc[mi][ni] = __builtin_amdgcn_mfma_f32_16x16x32_bf16(af[mi], bf[ni], acc[mi][ni], 0, 0, 0);
  }

  __syncthreads();  // main-loop LDS reads done; reuse sm for epilogue

  if (cls < 2) {
    // token-major C tile [128 tok][136], coalesced 128B-run readback
    const float qs = (cls == 0) ? CLOG2_ : 1.0f;   // fold softmax scale into Q
    #pragma unroll
    for (int mi = 0; mi < 4; mi++) {
      const int row0 = wm * 64 + mi * 16 + quad * 4;
      #pragma unroll
      for (int ni = 0; ni < 4; ni++) {
        const int col = wn * 64 + ni * 16 + l16;
        #pragma unroll
        for (int r = 0; r < 4; r++)
          sm[(row0 + r) * 136 + col] = f2bf(acc[mi][ni][r] * qs);
      }
    }
    __syncthreads();
    const int row = tid >> 1, half = tid & 1;
    const int t = t0 + row, bb = t >> 11, nn = t & (N_ - 1);
    const int cw = (c0 & 511) + half * 64;
    const int hh = cw >> 6;
    unsigned short* dst = ((cls == 0) ? qws : kws) +
                          ((size_t)(bb * H_ + hh) * N_ + nn) * D_;
    const unsigned short* srcp = &sm[row * 136 + half * 64];
    #pragma unroll
    for (int j = 0; j < 8; j++)
      *(uint4*)(dst + j * 8) = *(const uint4*)(srcp + j * 8);
  } else {
    // transposed C tile [128 col][136 tok], coalesced readback along n
    #pragma unroll
    for (int mi = 0; mi < 4; mi++) {
      const int tk = wm * 64 + mi * 16 + quad * 4;
      #pragma unroll
      for (int ni = 0; ni < 4; ni++) {
        const int col = wn * 64 + ni * 16 + l16;
        bs4 pk4 = pack4(acc[mi][ni][0], acc[mi][ni][1], acc[mi][ni][2], acc[mi][ni][3]);
        *(bs4*)&sm[col * 136 + tk] = pk4;
      }
    }
    __syncthreads();
    const int col = tid >> 1, half = tid & 1;
    const int cw = (c0 - 1024) + col;
    const int hh = cw >> 6, dd = cw & 63;
    const int bb = t0 >> 11, n0 = (t0 & (N_ - 1)) + half * 64;
    unsigned short* dst = vws + ((size_t)(bb * H_ + hh) * D_ + dd) * N_ + n0;
    const unsigned short* srcp = &sm[col * 136 + half * 64];
    #pragma unroll
    for (int j = 0; j < 8; j++)
      *(uint4*)(dst + j * 8) = *(const uint4*)(srcp + j * 8);
  }
}

// ---------------------------------------------------------------------------
// Kernel 2: flash attention. Transposed-S, unshifted exp2 (scale pre-folded
// into Q), q-tile 64, global_load_lds dbuf staging, 1 barrier/iter,
// XCD-chunked swizzle (R1: FETCH 69.7->12.3 MB, proven).
// R2: PV switched to K=32 MFMA. V-fragments are now contiguous 8-key
// granules -> ds_read_b128 with the same XOR slot pattern as K (verified
// conflict-free; the old b64 reads were the entire 8.49M conflict bill).
// P K=16 -> K=32 fragments assembled in-register with permlane32/16_swap
// (4 swaps per pair). PV: 20 K=16 MFMA + 16 b64 reads -> 10 K=32 MFMA +
// 8 b128 reads per iter.
// ---------------------------------------------------------------------------
__global__ __launch_bounds__(256) void attention_kernel(
    const unsigned short* __restrict__ qws,
    const unsigned short* __restrict__ kws,
    const unsigned short* __restrict__ vws,
    unsigned short* __restrict__ ows)
{
  __shared__ __attribute__((aligned(16))) unsigned short sm[2][8192];

  const int lid = blockIdx.x + (blockIdx.y << 5);      // grid (32,32), 0..1023
  const int swz = ((lid & 7) << 7) + (lid >> 3);       // bijective XCD chunking
  const int q0 = (swz & 31) * 64;                      // q-tile fast within chunk
  const int bh = swz >> 5;                             // 4 contiguous bh per XCD
  const int tid = threadIdx.x;
  const int wave = tid >> 6, lane = tid & 63;
  const int quad = lane >> 4, l16 = lane & 15;

  const unsigned short* qbase = qws + (size_t)bh * N_ * D_;
  const unsigned short* kbase = kws + (size_t)bh * N_ * D_;
  const unsigned short* vbase = vws + (size_t)bh * D_ * N_;

  const int qrow = q0 + wave * 16 + l16;
  short8 qf[2];
  #pragma unroll
  for (int kc = 0; kc < 2; kc++)
    qf[kc] = *(const short8*)(qbase + (size_t)qrow * D_ + kc * 32 + quad * 8);

  f32x4 ot[4];
  f32x4 otl;
  #pragma unroll
  for (int db = 0; db < 4; db++) ot[db] = (f32x4){0.f, 0.f, 0.f, 0.f};
  otl = (f32x4){0.f, 0.f, 0.f, 0.f};
  const short8 ones8 = {(short)0x3F80, (short)0x3F80, (short)0x3F80, (short)0x3F80,
                        (short)0x3F80, (short)0x3F80, (short)0x3F80, (short)0x3F80};

  const int r_ = tid >> 3;
  const int gc = (tid & 7) ^ (r_ & 7);
  const unsigned short* kst = kbase + (size_t)r_ * D_ + gc * 8;
  const unsigned short* vst = vbase + (size_t)r_ * N_ + gc * 8;

  {
    unsigned short* Ks = &sm[0][0];
    unsigned short* Vs = &sm[0][4096];
    gld16(kst,                 Ks + tid * 8);
    gld16(kst + 32 * D_,       Ks + 2048 + tid * 8);
    gld16(vst,                 Vs + tid * 8);
    gld16(vst + 32 * N_,       Vs + 2048 + tid * 8);
  }

  for (int kt = 0; kt < N_ / 64; kt++) {
    const int cur = kt & 1;
    __syncthreads();
    if (kt + 1 < N_ / 64) {
      const int k0 = (kt + 1) * 64;
      unsigned short* Ks = &sm[cur ^ 1][0];
      unsigned short* Vs = &sm[cur ^ 1][4096];
      gld16(kst + (size_t)k0 * D_,            Ks + tid * 8);
      gld16(kst + (size_t)(k0 + 32) * D_,     Ks + 2048 + tid * 8);
      gld16(vst + k0,                         Vs + tid * 8);
      gld16(vst + k0 + 32 * N_,               Vs + 2048 + tid * 8);
    }
    const unsigned short* Ks = &sm[cur][0];
    const unsigned short* Vs = &sm[cur][4096];

    f32x4 st[4];
    #pragma unroll
    for (int nb = 0; nb < 4; nb++) st[nb] = (f32x4){0.f, 0.f, 0.f, 0.f};
    #pragma unroll
    for (int kc = 0; kc < 2; kc++) {
      const int sw = (((kc * 4 + quad) ^ (l16 & 7)) << 3);
      #pragma unroll
      for (int nb = 0; nb < 4; nb++) {
        short8 kf = *(const short8*)&Ks[(nb * 16 + l16) * 64 + sw];
        st[nb] = __builtin_amdgcn_mfma_f32_16x16x32_bf16(kf, qf[kc], st[nb], 0, 0, 0);
      }
    }

    bs4 pf[4];
    #pragma unroll
    for (int nb = 0; nb < 4; nb++) {
      float p0 = __builtin_amdgcn_exp2f(st[nb][0]);
      float p1 = __builtin_amdgcn_exp2f(st[nb][1]);
      float p2 = __builtin_amdgcn_exp2f(st[nb][2]);
      float p3 = __builtin_amdgcn_exp2f(st[nb][3]);
      pf[nb] = pack4(p0, p1, p2, p3);
    }

    // K=32 P-fragments: keys 0-31 from (pf0,pf1), keys 32-63 from (pf2,pf3)
    const short8 pA0 = assemble_p(pf[0], pf[1]);
    const short8 pA1 = assemble_p(pf[2], pf[3]);

    #pragma unroll
    for (int h = 0; h < 2; h++) {
      const short8 pA = h ? pA1 : pA0;
      const int slot = (((h * 4 + quad) ^ (l16 & 7)) << 3);
      #pragma unroll
      for (int db = 0; db < 4; db++) {
        short8 vf8 = *(const short8*)&Vs[(db * 16 + l16) * 64 + slot];
        ot[db] = __builtin_amdgcn_mfma_f32_16x16x32_bf16(vf8, pA, ot[db], 0, 0, 0);
      }
      otl = __builtin_amdgcn_mfma_f32_16x16x32_bf16(ones8, pA, otl, 0, 0, 0);
    }
  }

  const float inv = 1.f / otl[0];
  __syncthreads();
  unsigned short* Os = (unsigned short*)sm;   // 64 x 72 overlay
  #pragma unroll
  for (int db = 0; db < 4; db++) {
    bs4 pk4 = pack4(ot[db][0] * inv, ot[db][1] * inv, ot[db][2] * inv, ot[db][3] * inv);
    *(bs4*)&Os[(wave * 16 + l16) * 72 + db * 16 + quad * 4] = pk4;
  }
  __syncthreads();
  const int b_ = bh >> 3, h_ = bh & 7;
  const int qloc = tid >> 2, chunk = tid & 3;
  unsigned short* dst = ows + ((size_t)b_ * N_ + q0 + qloc) * (H_ * D_) + h_ * 64 + chunk * 16;
  const unsigned short* srcp = &Os[qloc * 72 + chunk * 16];
  *(uint4*)dst = *(const uint4*)srcp;
  *(uint4*)(dst + 8) = *(const uint4*)(srcp + 8);
}

// ---------------------------------------------------------------------------
// Kernel 3: output projection. 128x64 tile, BK=32, DOUBLE-BUFFERED
// global_load_lds staging (one barrier/iter). fp32 out + bias, 64B-run stores.
// XCD-chunked block swizzle (T1, bijective: 512%8==0).
// ---------------------------------------------------------------------------
__global__ __launch_bounds__(256) void out_gemm_kernel(
    const unsigned short* __restrict__ ain, const unsigned short* __restrict__ wobf,
    const float* __restrict__ bo, float* __restrict__ y)
{
  // buf b at sm + b*6144: A 4096 | B 2048 shorts; total 12288 shorts = 24 KB
  __shared__ __attribute__((aligned(16))) unsigned short sm[12288];

  const int lid = blockIdx.x + (blockIdx.y << 6);      // grid (64,8), 0..511
  const int swz = ((lid & 7) << 6) + (lid >> 3);       // bijective XCD chunking
  const int t0 = (swz >> 3) * 128;
  const int c0 = (swz & 7) * 64;
  const int tid = threadIdx.x;
  const int wave = tid >> 6, lane = tid & 63;
  const int quad = lane >> 4, l16 = lane & 15;

  const int r_ = tid >> 2;
  const int gc = (tid & 3) ^ (r_ & 3);
  const unsigned short* abase = ain  + (size_t)(t0 + r_) * IN_ + gc * 8;
  const unsigned short* bbase = wobf + (size_t)(c0 + r_) * IN_ + gc * 8;

  auto stage = [&](int k0, int buf) {
    unsigned short* sA = sm + buf * 6144;
    unsigned short* sB = sA + 4096;
    gld16(abase + k0,            sA + tid * 8);
    gld16(abase + 64 * IN_ + k0, sA + 2048 + tid * 8);
    gld16(bbase + k0,            sB + tid * 8);     // B: 64 rows x 4 granules = 256 slots
  };

  f32x4 acc[2][4];
  #pragma unroll
  for (int i = 0; i < 2; i++)
    #pragma unroll
    for (int j = 0; j < 4; j++) acc[i][j] = (f32x4){0.f, 0.f, 0.f, 0.f};

  stage(0, 0);

  for (int kt = 0; kt < 16; kt++) {
    const int cur = kt & 1;
    __syncthreads();
    if (kt + 1 < 16) stage((kt + 1) * 32, cur ^ 1);
    const unsigned short* sA = sm + cur * 6144;
    const unsigned short* sB = sA + 4096;
    const int sw = ((quad ^ (l16 & 3)) << 3);
    short8 af[2], bf[4];
    #pragma unroll
    for (int mi = 0; mi < 2; mi++)
      af[mi] = *(const short8*)&sA[(wave * 32 + mi * 16 + l16) * 32 + sw];
    #pragma unroll
    for (int ni = 0; ni < 4; ni++)
      bf[ni] = *(const short8*)&sB[(ni * 16 + l16) * 32 + sw];
    #pragma unroll
    for (int mi = 0; mi < 2; mi++)
      #pragma unroll
      for (int ni = 0; ni < 4; ni++)
        acc[mi][ni] = __builtin_amdgcn_mfma_f32_16x16x32_bf16(af[mi], bf[ni], acc[mi][ni], 0, 0, 0);
  }

  #pragma unroll
  for (int mi = 0; mi < 2; mi++) {
    const int t = t0 + wave * 32 + mi * 16 + quad * 4;
    #pragma unroll
    for (int ni = 0; ni < 4; ni++) {
      const int c = c0 + ni * 16 + l16;
      const float bias = bo[c];
      float* dst = y + (size_t)t * IN_ + c;
      dst[0]        = acc[mi][ni][0] + bias;
      dst[IN_]      = acc[mi][ni][1] + bias;
      dst[2 * IN_]  = acc[mi][ni][2] + bias;
      dst[3 * IN_]  = acc[mi][ni][3] + bias;
    }
  }
}

extern "C" void kernel_launch(void* const* d_in, const int* in_sizes, int n_in,
                              void* d_out, int out_size, void* d_ws, size_t ws_size,
                              hipStream_t stream) {
  const float* x   = (const float*)d_in[0];
  const float* Wq  = (const float*)d_in[1];
  const float* Wkv = (const float*)d_in[2];
  const float* Wo  = (const float*)d_in[3];
  const float* bo  = (const float*)d_in[4];
  float* out = (float*)d_out;

  // ws (shorts): qws 4M | kws 4M | vws 4M | ows 4M | wbf 768K | wobf 256K  (~34 MB, proven)
  unsigned short* qws  = (unsigned short*)d_ws;
  unsigned short* kws  = qws + (size_t)TOK_ * 512;
  unsigned short* vws  = kws + (size_t)TOK_ * 512;
  unsigned short* ows  = vws + (size_t)TOK_ * 512;
  unsigned short* wbf  = ows + (size_t)TOK_ * 512;       // [Wq 512 | Wkv 1024] x 512
  unsigned short* wobf = wbf + (size_t)1536 * 512;
  unsigned short* xbf  = ows;  // alias: consumed by qkv before attention writes ows

  conv_all_kernel<<<dim3(2560), 256, 0, stream>>>(x, Wq, Wkv, Wo, xbf, wbf, wobf);
  qkv_gemm_kernel<<<dim3(TOK_ / 128, 1536 / 128), 256, 0, stream>>>(xbf, wbf, qws, kws, vws);
  attention_kernel<<<dim3(N_ / 64, B_ * H_), 256, 0, stream>>>(qws, kws, vws, ows);
  out_gemm_kernel<<<dim3(TOK_ / 128, 512 / 64), 256, 0, stream>>>(ows, wobf, bo, out);
}

// Round 3
// 158.346 us; speedup vs baseline: 1.0970x; 1.0454x over previous
//
#include <hip/hip_runtime.h>
#include <hip/hip_bf16.h>

#define H_ 8
#define D_ 64
#define IN_ 512
#define B_ 4
#define N_ 2048
#define TOK_ (B_*N_)
// softmax in exp2 domain: scale * log2(e) (folded into Q at projection time)
#define CLOG2_ 0.18033688011112042f

typedef __attribute__((ext_vector_type(8))) short short8;
typedef __attribute__((ext_vector_type(4))) short bs4;
typedef __attribute__((ext_vector_type(4))) float f32x4;

__device__ __forceinline__ unsigned short f2bf(float f) {
  unsigned int u = __float_as_uint(f);
  u += 0x7FFFu + ((u >> 16) & 1u);
  return (unsigned short)(u >> 16);
}

// packed converts: v_cvt_pk_bf16_f32
__device__ __forceinline__ short8 cvt8(const float4 a, const float4 b) {
  union { short8 v; __hip_bfloat162 h[4]; } z;
  z.h[0] = __float22bfloat162_rn(make_float2(a.x, a.y));
  z.h[1] = __float22bfloat162_rn(make_float2(a.z, a.w));
  z.h[2] = __float22bfloat162_rn(make_float2(b.x, b.y));
  z.h[3] = __float22bfloat162_rn(make_float2(b.z, b.w));
  return z.v;
}

__device__ __forceinline__ bs4 pack4(float a, float b, float c, float d) {
  union { bs4 v; __hip_bfloat162 h[2]; } z;
  z.h[0] = __float22bfloat162_rn(make_float2(a, b));
  z.h[1] = __float22bfloat162_rn(make_float2(c, d));
  return z.v;
}

// Reassemble two K=16 P-fragments (keys nb*16+quad*4+r layout) into one K=32
// B-fragment (keys quad*8+j layout) with 4 lane-swaps.
__device__ __forceinline__ short8 assemble_p(bs4 pa, bs4 pb) {
  union { bs4 v; unsigned int w[2]; } A, B;
  A.v = pa; B.v = pb;
  auto s0 = __builtin_amdgcn_permlane32_swap(A.w[0], B.w[0], false, false);
  auto s1 = __builtin_amdgcn_permlane32_swap(A.w[1], B.w[1], false, false);
  auto t0 = __builtin_amdgcn_permlane16_swap(s0[0], s0[1], false, false);
  auto t1 = __builtin_amdgcn_permlane16_swap(s1[0], s1[1], false, false);
  union { short8 v; unsigned int w[4]; } R;
  R.w[0] = t0[0];   // j=0,1
  R.w[1] = t1[0];   // j=2,3
  R.w[2] = t0[1];   // j=4,5
  R.w[3] = t1[1];   // j=6,7
  return R.v;
}

// async global->LDS, 16B per lane; dest = wave-uniform base + lane*16
__device__ __forceinline__ void gld16(const unsigned short* g, unsigned short* l) {
  __builtin_amdgcn_global_load_lds(
      (const __attribute__((address_space(1))) void*)g,
      (__attribute__((address_space(3))) void*)l, 16, 0, 0);
}

// ---------------------------------------------------------------------------
// Kernel 0: merged fp32 -> bf16 convert (x, Wq, Wkv, Wo) in ONE launch.
// ---------------------------------------------------------------------------
__global__ __launch_bounds__(256) void conv_all_kernel(
    const float* __restrict__ x, const float* __restrict__ Wq,
    const float* __restrict__ Wkv, const float* __restrict__ Wo,
    unsigned short* __restrict__ xbf, unsigned short* __restrict__ wbf,
    unsigned short* __restrict__ wobf)
{
  const int b = blockIdx.x;
  const float* src;
  unsigned short* dst;
  size_t base;
  if (b < 2048)      { src = x;   dst = xbf;             base = (size_t)b * 2048; }
  else if (b < 2176) { src = Wq;  dst = wbf;             base = (size_t)(b - 2048) * 2048; }
  else if (b < 2432) { src = Wkv; dst = wbf + 512 * 512; base = (size_t)(b - 2176) * 2048; }
  else               { src = Wo;  dst = wobf;            base = (size_t)(b - 2432) * 2048; }
  size_t i = base + (size_t)threadIdx.x * 8;
  float4 a = *(const float4*)(src + i);
  float4 c = *(const float4*)(src + i + 4);
  *(short8*)(dst + i) = cvt8(a, c);
}

// ---------------------------------------------------------------------------
// Kernel 1: QKV projection. 128x128 tile, BK=32, DOUBLE-BUFFERED
// global_load_lds staging, source-permuted XOR swizzle.
// Q pre-scaled by CLOG2_. Q,K -> [b,h,n,d]; V -> [b,h,d,n]. LDS epilogues.
// XCD-chunked block swizzle (T1, bijective: 768%8==0).
// ---------------------------------------------------------------------------
__global__ __launch_bounds__(256) void qkv_gemm_kernel(
    const unsigned short* __restrict__ xbf, const unsigned short* __restrict__ wbf,
    unsigned short* __restrict__ qws, unsigned short* __restrict__ kws,
    unsigned short* __restrict__ vws)
{
  // staging: buf b at sm + b*8192 (A 4096 | B 4096 shorts); epilogue overlay 128*136
  __shared__ __attribute__((aligned(16))) unsigned short sm[128 * 136];

  const int lid = blockIdx.x + (blockIdx.y << 6);      // grid (64,12), 0..767
  const int swz = (lid & 7) * 96 + (lid >> 3);         // bijective XCD chunking
  const int t0 = (swz / 12) * 128;
  const int c0 = (swz % 12) * 128;                     // 0..1535 over [Wq|Wkv] rows
  const int cls = c0 >> 9;                             // 0=q 1=k 2=v

  const int tid = threadIdx.x;
  const int wave = tid >> 6, lane = tid & 63;
  const int quad = lane >> 4, l16 = lane & 15;
  const int wm = wave >> 1, wn = wave & 1;

  // staging source: row r = i*64 + tid>>2, granule gc = (tid&3)^(r&3)
  const int r_ = tid >> 2;
  const int gc = (tid & 3) ^ (r_ & 3);
  const unsigned short* abase = xbf + (size_t)(t0 + r_) * IN_ + gc * 8;
  const unsigned short* bbase = wbf + (size_t)(c0 + r_) * IN_ + gc * 8;

  auto stage = [&](int k0, int buf) {
    unsigned short* sA = sm + buf * 8192;
    unsigned short* sB = sA + 4096;
    gld16(abase + k0,            sA + tid * 8);
    gld16(abase + 64 * IN_ + k0, sA + 2048 + tid * 8);
    gld16(bbase + k0,            sB + tid * 8);
    gld16(bbase + 64 * IN_ + k0, sB + 2048 + tid * 8);
  };

  f32x4 acc[4][4];
  #pragma unroll
  for (int i = 0; i < 4; i++)
    #pragma unroll
    for (int j = 0; j < 4; j++) acc[i][j] = (f32x4){0.f, 0.f, 0.f, 0.f};

  stage(0, 0);

  for (int kt = 0; kt < 16; kt++) {
    const int cur = kt & 1;
    __syncthreads();                       // tile kt landed; prev compute done
    if (kt + 1 < 16) stage((kt + 1) * 32, cur ^ 1);
    const unsigned short* sA = sm + cur * 8192;
    const unsigned short* sB = sA + 4096;
    const int sw = ((quad ^ (l16 & 3)) << 3);
    short8 af[4], bf[4];
    #pragma unroll
    for (int mi = 0; mi < 4; mi++)
      af[mi] = *(const short8*)&sA[(wm * 64 + mi * 16 + l16) * 32 + sw];
    #pragma unroll
    for (int ni = 0; ni < 4; ni++)
      bf[ni] = *(const short8*)&sB[(wn * 64 + ni * 16 + l16) * 32 + sw];
    #pragma unroll
    for (int mi = 0; mi < 4; mi++)
      #pragma unroll
      for (int ni = 0; ni < 4; ni++)
        acc[mi][ni] = __builtin_amdgcn_mfma_f32_16x16x32_bf16(af[mi], bf[ni], acc[mi][ni], 0, 0, 0);
  }

  __syncthreads();  // main-loop LDS reads done; reuse sm for epilogue

  if (cls < 2) {
    // token-major C tile [128 tok][136], coalesced 128B-run readback
    const float qs = (cls == 0) ? CLOG2_ : 1.0f;   // fold softmax scale into Q
    #pragma unroll
    for (int mi = 0; mi < 4; mi++) {
      const int row0 = wm * 64 + mi * 16 + quad * 4;
      #pragma unroll
      for (int ni = 0; ni < 4; ni++) {
        const int col = wn * 64 + ni * 16 + l16;
        #pragma unroll
        for (int r = 0; r < 4; r++)
          sm[(row0 + r) * 136 + col] = f2bf(acc[mi][ni][r] * qs);
      }
    }
    __syncthreads();
    const int row = tid >> 1, half = tid & 1;
    const int t = t0 + row, bb = t >> 11, nn = t & (N_ - 1);
    const int cw = (c0 & 511) + half * 64;
    const int hh = cw >> 6;
    unsigned short* dst = ((cls == 0) ? qws : kws) +
                          ((size_t)(bb * H_ + hh) * N_ + nn) * D_;
    const unsigned short* srcp = &sm[row * 136 + half * 64];
    #pragma unroll
    for (int j = 0; j < 8; j++)
      *(uint4*)(dst + j * 8) = *(const uint4*)(srcp + j * 8);
  } else {
    // transposed C tile [128 col][136 tok], coalesced readback along n
    #pragma unroll
    for (int mi = 0; mi < 4; mi++) {
      const int tk = wm * 64 + mi * 16 + quad * 4;
      #pragma unroll
      for (int ni = 0; ni < 4; ni++) {
        const int col = wn * 64 + ni * 16 + l16;
        bs4 pk4 = pack4(acc[mi][ni][0], acc[mi][ni][1], acc[mi][ni][2], acc[mi][ni][3]);
        *(bs4*)&sm[col * 136 + tk] = pk4;
      }
    }
    __syncthreads();
    const int col = tid >> 1, half = tid & 1;
    const int cw = (c0 - 1024) + col;
    const int hh = cw >> 6, dd = cw & 63;
    const int bb = t0 >> 11, n0 = (t0 & (N_ - 1)) + half * 64;
    unsigned short* dst = vws + ((size_t)(bb * H_ + hh) * D_ + dd) * N_ + n0;
    const unsigned short* srcp = &sm[col * 136 + half * 64];
    #pragma unroll
    for (int j = 0; j < 8; j++)
      *(uint4*)(dst + j * 8) = *(const uint4*)(srcp + j * 8);
  }
}

// ---------------------------------------------------------------------------
// Kernel 2: flash attention. Transposed-S, unshifted exp2 (scale pre-folded
// into Q), global_load_lds dbuf staging, 1 barrier/iter, XCD swizzle (R1),
// K=32 PV with permlane P-assembly (R2: conflicts 8.49M->98K).
// R3: q-tile 64 -> 128 per block (2 row-blocks per wave).
//  - each K/V fragment read feeds 2 MFMAs (LDS reads per MFMA halved)
//  - K/V staging + barrier per q-row halved
//  - 2 independent dependency chains per wave (ILP x2 in the serial
//    QK->exp2->pack->PV chain); grid 1024 -> 512 (2 blocks/CU).
// ---------------------------------------------------------------------------
__global__ __launch_bounds__(256) void attention_kernel(
    const unsigned short* __restrict__ qws,
    const unsigned short* __restrict__ kws,
    const unsigned short* __restrict__ vws,
    unsigned short* __restrict__ ows)
{
  __shared__ __attribute__((aligned(16))) unsigned short sm[2][8192];

  const int lid = blockIdx.x + (blockIdx.y << 4);      // grid (16,32), 0..511
  const int swz = ((lid & 7) << 6) + (lid >> 3);       // bijective XCD chunking
  const int q0 = (swz & 15) * 128;                     // q-tile fast within chunk
  const int bh = swz >> 4;                             // 4 contiguous bh per XCD
  const int tid = threadIdx.x;
  const int wave = tid >> 6, lane = tid & 63;
  const int quad = lane >> 4, l16 = lane & 15;

  const unsigned short* qbase = qws + (size_t)bh * N_ * D_;
  const unsigned short* kbase = kws + (size_t)bh * N_ * D_;
  const unsigned short* vbase = vws + (size_t)bh * D_ * N_;

  // two q row-blocks per wave: rows q0 + rb*64 + wave*16 + l16
  short8 qf[2][2];
  #pragma unroll
  for (int rb = 0; rb < 2; rb++) {
    const int qrow = q0 + rb * 64 + wave * 16 + l16;
    #pragma unroll
    for (int kc = 0; kc < 2; kc++)
      qf[rb][kc] = *(const short8*)(qbase + (size_t)qrow * D_ + kc * 32 + quad * 8);
  }

  f32x4 ot[2][4];
  f32x4 otl[2];
  #pragma unroll
  for (int rb = 0; rb < 2; rb++) {
    #pragma unroll
    for (int db = 0; db < 4; db++) ot[rb][db] = (f32x4){0.f, 0.f, 0.f, 0.f};
    otl[rb] = (f32x4){0.f, 0.f, 0.f, 0.f};
  }
  const short8 ones8 = {(short)0x3F80, (short)0x3F80, (short)0x3F80, (short)0x3F80,
                        (short)0x3F80, (short)0x3F80, (short)0x3F80, (short)0x3F80};

  const int r_ = tid >> 3;
  const int gc = (tid & 7) ^ (r_ & 7);
  const unsigned short* kst = kbase + (size_t)r_ * D_ + gc * 8;
  const unsigned short* vst = vbase + (size_t)r_ * N_ + gc * 8;

  {
    unsigned short* Ks = &sm[0][0];
    unsigned short* Vs = &sm[0][4096];
    gld16(kst,                 Ks + tid * 8);
    gld16(kst + 32 * D_,       Ks + 2048 + tid * 8);
    gld16(vst,                 Vs + tid * 8);
    gld16(vst + 32 * N_,       Vs + 2048 + tid * 8);
  }

  for (int kt = 0; kt < N_ / 64; kt++) {
    const int cur = kt & 1;
    __syncthreads();
    if (kt + 1 < N_ / 64) {
      const int k0 = (kt + 1) * 64;
      unsigned short* Ks = &sm[cur ^ 1][0];
      unsigned short* Vs = &sm[cur ^ 1][4096];
      gld16(kst + (size_t)k0 * D_,            Ks + tid * 8);
      gld16(kst + (size_t)(k0 + 32) * D_,     Ks + 2048 + tid * 8);
      gld16(vst + k0,                         Vs + tid * 8);
      gld16(vst + k0 + 32 * N_,               Vs + 2048 + tid * 8);
    }
    const unsigned short* Ks = &sm[cur][0];
    const unsigned short* Vs = &sm[cur][4096];

    // QK^T: each K fragment feeds both row-blocks
    f32x4 st[2][4];
    #pragma unroll
    for (int rb = 0; rb < 2; rb++)
      #pragma unroll
      for (int nb = 0; nb < 4; nb++) st[rb][nb] = (f32x4){0.f, 0.f, 0.f, 0.f};
    #pragma unroll
    for (int kc = 0; kc < 2; kc++) {
      const int sw = (((kc * 4 + quad) ^ (l16 & 7)) << 3);
      #pragma unroll
      for (int nb = 0; nb < 4; nb++) {
        short8 kf = *(const short8*)&Ks[(nb * 16 + l16) * 64 + sw];
        st[0][nb] = __builtin_amdgcn_mfma_f32_16x16x32_bf16(kf, qf[0][kc], st[0][nb], 0, 0, 0);
        st[1][nb] = __builtin_amdgcn_mfma_f32_16x16x32_bf16(kf, qf[1][kc], st[1][nb], 0, 0, 0);
      }
    }

    // softmax numerators + K=32 P-fragment assembly, per row-block
    short8 pA[2][2];
    #pragma unroll
    for (int rb = 0; rb < 2; rb++) {
      bs4 pf[4];
      #pragma unroll
      for (int nb = 0; nb < 4; nb++) {
        float p0 = __builtin_amdgcn_exp2f(st[rb][nb][0]);
        float p1 = __builtin_amdgcn_exp2f(st[rb][nb][1]);
        float p2 = __builtin_amdgcn_exp2f(st[rb][nb][2]);
        float p3 = __builtin_amdgcn_exp2f(st[rb][nb][3]);
        pf[nb] = pack4(p0, p1, p2, p3);
      }
      pA[rb][0] = assemble_p(pf[0], pf[1]);
      pA[rb][1] = assemble_p(pf[2], pf[3]);
    }

    // PV: each V fragment feeds both row-blocks
    #pragma unroll
    for (int h = 0; h < 2; h++) {
      const int slot = (((h * 4 + quad) ^ (l16 & 7)) << 3);
      short8 vf8[4];
      #pragma unroll
      for (int db = 0; db < 4; db++)
        vf8[db] = *(const short8*)&Vs[(db * 16 + l16) * 64 + slot];
      #pragma unroll
      for (int rb = 0; rb < 2; rb++) {
        #pragma unroll
        for (int db = 0; db < 4; db++)
          ot[rb][db] = __builtin_amdgcn_mfma_f32_16x16x32_bf16(vf8[db], pA[rb][h], ot[rb][db], 0, 0, 0);
        otl[rb] = __builtin_amdgcn_mfma_f32_16x16x32_bf16(ones8, pA[rb][h], otl[rb], 0, 0, 0);
      }
    }
  }

  const float inv0 = 1.f / otl[0][0];
  const float inv1 = 1.f / otl[1][0];
  __syncthreads();
  unsigned short* Os = (unsigned short*)sm;   // 128 x 72 overlay (18 KB)
  #pragma unroll
  for (int rb = 0; rb < 2; rb++) {
    const float inv = rb ? inv1 : inv0;
    #pragma unroll
    for (int db = 0; db < 4; db++) {
      bs4 pk4 = pack4(ot[rb][db][0] * inv, ot[rb][db][1] * inv,
                      ot[rb][db][2] * inv, ot[rb][db][3] * inv);
      *(bs4*)&Os[(rb * 64 + wave * 16 + l16) * 72 + db * 16 + quad * 4] = pk4;
    }
  }
  __syncthreads();
  const int b_ = bh >> 3, h_ = bh & 7;
  const int qloc = tid >> 1, chunk = tid & 1;   // 128 rows x 2 threads, 64B each
  unsigned short* dst = ows + ((size_t)b_ * N_ + q0 + qloc) * (H_ * D_) + h_ * 64 + chunk * 32;
  const unsigned short* srcp = &Os[qloc * 72 + chunk * 32];
  #pragma unroll
  for (int j = 0; j < 4; j++)
    *(uint4*)(dst + j * 8) = *(const uint4*)(srcp + j * 8);
}

// ---------------------------------------------------------------------------
// Kernel 3: output projection. 128x64 tile, BK=32, DOUBLE-BUFFERED
// global_load_lds staging. fp32 out + bias, 64B-run stores.
// XCD-chunked block swizzle (T1, bijective: 512%8==0).
// ---------------------------------------------------------------------------
__global__ __launch_bounds__(256) void out_gemm_kernel(
    const unsigned short* __restrict__ ain, const unsigned short* __restrict__ wobf,
    const float* __restrict__ bo, float* __restrict__ y)
{
  // buf b at sm + b*6144: A 4096 | B 2048 shorts; total 12288 shorts = 24 KB
  __shared__ __attribute__((aligned(16))) unsigned short sm[12288];

  const int lid = blockIdx.x + (blockIdx.y << 6);      // grid (64,8), 0..511
  const int swz = ((lid & 7) << 6) + (lid >> 3);       // bijective XCD chunking
  const int t0 = (swz >> 3) * 128;
  const int c0 = (swz & 7) * 64;
  const int tid = threadIdx.x;
  const int wave = tid >> 6, lane = tid & 63;
  const int quad = lane >> 4, l16 = lane & 15;

  const int r_ = tid >> 2;
  const int gc = (tid & 3) ^ (r_ & 3);
  const unsigned short* abase = ain  + (size_t)(t0 + r_) * IN_ + gc * 8;
  const unsigned short* bbase = wobf + (size_t)(c0 + r_) * IN_ + gc * 8;

  auto stage = [&](int k0, int buf) {
    unsigned short* sA = sm + buf * 6144;
    unsigned short* sB = sA + 4096;
    gld16(abase + k0,            sA + tid * 8);
    gld16(abase + 64 * IN_ + k0, sA + 2048 + tid * 8);
    gld16(bbase + k0,            sB + tid * 8);     // B: 64 rows x 4 granules = 256 slots
  };

  f32x4 acc[2][4];
  #pragma unroll
  for (int i = 0; i < 2; i++)
    #pragma unroll
    for (int j = 0; j < 4; j++) acc[i][j] = (f32x4){0.f, 0.f, 0.f, 0.f};

  stage(0, 0);

  for (int kt = 0; kt < 16; kt++) {
    const int cur = kt & 1;
    __syncthreads();
    if (kt + 1 < 16) stage((kt + 1) * 32, cur ^ 1);
    const unsigned short* sA = sm + cur * 6144;
    const unsigned short* sB = sA + 4096;
    const int sw = ((quad ^ (l16 & 3)) << 3);
    short8 af[2], bf[4];
    #pragma unroll
    for (int mi = 0; mi < 2; mi++)
      af[mi] = *(const short8*)&sA[(wave * 32 + mi * 16 + l16) * 32 + sw];
    #pragma unroll
    for (int ni = 0; ni < 4; ni++)
      bf[ni] = *(const short8*)&sB[(ni * 16 + l16) * 32 + sw];
    #pragma unroll
    for (int mi = 0; mi < 2; mi++)
      #pragma unroll
      for (int ni = 0; ni < 4; ni++)
        acc[mi][ni] = __builtin_amdgcn_mfma_f32_16x16x32_bf16(af[mi], bf[ni], acc[mi][ni], 0, 0, 0);
  }

  #pragma unroll
  for (int mi = 0; mi < 2; mi++) {
    const int t = t0 + wave * 32 + mi * 16 + quad * 4;
    #pragma unroll
    for (int ni = 0; ni < 4; ni++) {
      const int c = c0 + ni * 16 + l16;
      const float bias = bo[c];
      float* dst = y + (size_t)t * IN_ + c;
      dst[0]        = acc[mi][ni][0] + bias;
      dst[IN_]      = acc[mi][ni][1] + bias;
      dst[2 * IN_]  = acc[mi][ni][2] + bias;
      dst[3 * IN_]  = acc[mi][ni][3] + bias;
    }
  }
}

extern "C" void kernel_launch(void* const* d_in, const int* in_sizes, int n_in,
                              void* d_out, int out_size, void* d_ws, size_t ws_size,
                              hipStream_t stream) {
  const float* x   = (const float*)d_in[0];
  const float* Wq  = (const float*)d_in[1];
  const float* Wkv = (const float*)d_in[2];
  const float* Wo  = (const float*)d_in[3];
  const float* bo  = (const float*)d_in[4];
  float* out = (float*)d_out;

  // ws (shorts): qws 4M | kws 4M | vws 4M | ows 4M | wbf 768K | wobf 256K  (~34 MB, proven)
  unsigned short* qws  = (unsigned short*)d_ws;
  unsigned short* kws  = qws + (size_t)TOK_ * 512;
  unsigned short* vws  = kws + (size_t)TOK_ * 512;
  unsigned short* ows  = vws + (size_t)TOK_ * 512;
  unsigned short* wbf  = ows + (size_t)TOK_ * 512;       // [Wq 512 | Wkv 1024] x 512
  unsigned short* wobf = wbf + (size_t)1536 * 512;
  unsigned short* xbf  = ows;  // alias: consumed by qkv before attention writes ows

  conv_all_kernel<<<dim3(2560), 256, 0, stream>>>(x, Wq, Wkv, Wo, xbf, wbf, wobf);
  qkv_gemm_kernel<<<dim3(TOK_ / 128, 1536 / 128), 256, 0, stream>>>(xbf, wbf, qws, kws, vws);
  attention_kernel<<<dim3(N_ / 128, B_ * H_), 256, 0, stream>>>(qws, kws, vws, ows);
  out_gemm_kernel<<<dim3(TOK_ / 128, 512 / 64), 256, 0, stream>>>(ows, wobf, bo, out);
}

// Round 4
// 152.411 us; speedup vs baseline: 1.1398x; 1.0389x over previous
//
#include <hip/hip_runtime.h>
#include <hip/hip_bf16.h>

#define H_ 8
#define D_ 64
#define IN_ 512
#define B_ 4
#define N_ 2048
#define TOK_ (B_*N_)
// softmax in exp2 domain: scale * log2(e) (folded into Q at projection time)
#define CLOG2_ 0.18033688011112042f

typedef __attribute__((ext_vector_type(8))) short short8;
typedef __attribute__((ext_vector_type(4))) short bs4;
typedef __attribute__((ext_vector_type(4))) float f32x4;

__device__ __forceinline__ unsigned short f2bf(float f) {
  unsigned int u = __float_as_uint(f);
  u += 0x7FFFu + ((u >> 16) & 1u);
  return (unsigned short)(u >> 16);
}

// packed converts: v_cvt_pk_bf16_f32
__device__ __forceinline__ short8 cvt8(const float4 a, const float4 b) {
  union { short8 v; __hip_bfloat162 h[4]; } z;
  z.h[0] = __float22bfloat162_rn(make_float2(a.x, a.y));
  z.h[1] = __float22bfloat162_rn(make_float2(a.z, a.w));
  z.h[2] = __float22bfloat162_rn(make_float2(b.x, b.y));
  z.h[3] = __float22bfloat162_rn(make_float2(b.z, b.w));
  return z.v;
}

__device__ __forceinline__ bs4 pack4(float a, float b, float c, float d) {
  union { bs4 v; __hip_bfloat162 h[2]; } z;
  z.h[0] = __float22bfloat162_rn(make_float2(a, b));
  z.h[1] = __float22bfloat162_rn(make_float2(c, d));
  return z.v;
}

// Reassemble two K=16 P-fragments (keys nb*16+quad*4+r layout) into one K=32
// B-fragment (keys quad*8+j layout) with 4 lane-swaps.
__device__ __forceinline__ short8 assemble_p(bs4 pa, bs4 pb) {
  union { bs4 v; unsigned int w[2]; } A, B;
  A.v = pa; B.v = pb;
  auto s0 = __builtin_amdgcn_permlane32_swap(A.w[0], B.w[0], false, false);
  auto s1 = __builtin_amdgcn_permlane32_swap(A.w[1], B.w[1], false, false);
  auto t0 = __builtin_amdgcn_permlane16_swap(s0[0], s0[1], false, false);
  auto t1 = __builtin_amdgcn_permlane16_swap(s1[0], s1[1], false, false);
  union { short8 v; unsigned int w[4]; } R;
  R.w[0] = t0[0];   // j=0,1
  R.w[1] = t1[0];   // j=2,3
  R.w[2] = t0[1];   // j=4,5
  R.w[3] = t1[1];   // j=6,7
  return R.v;
}

// async global->LDS, 16B per lane; dest = wave-uniform base + lane*16
__device__ __forceinline__ void gld16(const unsigned short* g, unsigned short* l) {
  __builtin_amdgcn_global_load_lds(
      (const __attribute__((address_space(1))) void*)g,
      (__attribute__((address_space(3))) void*)l, 16, 0, 0);
}

// ---------------------------------------------------------------------------
// Kernel 0: merged fp32 -> bf16 convert (x, Wq, Wkv, Wo) in ONE launch.
// ---------------------------------------------------------------------------
__global__ __launch_bounds__(256) void conv_all_kernel(
    const float* __restrict__ x, const float* __restrict__ Wq,
    const float* __restrict__ Wkv, const float* __restrict__ Wo,
    unsigned short* __restrict__ xbf, unsigned short* __restrict__ wbf,
    unsigned short* __restrict__ wobf)
{
  const int b = blockIdx.x;
  const float* src;
  unsigned short* dst;
  size_t base;
  if (b < 2048)      { src = x;   dst = xbf;             base = (size_t)b * 2048; }
  else if (b < 2176) { src = Wq;  dst = wbf;             base = (size_t)(b - 2048) * 2048; }
  else if (b < 2432) { src = Wkv; dst = wbf + 512 * 512; base = (size_t)(b - 2176) * 2048; }
  else               { src = Wo;  dst = wobf;            base = (size_t)(b - 2432) * 2048; }
  size_t i = base + (size_t)threadIdx.x * 8;
  float4 a = *(const float4*)(src + i);
  float4 c = *(const float4*)(src + i + 4);
  *(short8*)(dst + i) = cvt8(a, c);
}

// ---------------------------------------------------------------------------
// Kernel 1: QKV projection. 128x128 tile, BK=32, DOUBLE-BUFFERED
// global_load_lds staging, source-permuted XOR swizzle.
// Q pre-scaled by CLOG2_. Q,K -> [b,h,n,d]; V -> [b,h,d,n]. LDS epilogues.
// XCD-chunked block swizzle (T1, bijective: 768%8==0).
// ---------------------------------------------------------------------------
__global__ __launch_bounds__(256) void qkv_gemm_kernel(
    const unsigned short* __restrict__ xbf, const unsigned short* __restrict__ wbf,
    unsigned short* __restrict__ qws, unsigned short* __restrict__ kws,
    unsigned short* __restrict__ vws)
{
  // staging: buf b at sm + b*8192 (A 4096 | B 4096 shorts); epilogue overlay 128*136
  __shared__ __attribute__((aligned(16))) unsigned short sm[128 * 136];

  const int lid = blockIdx.x + (blockIdx.y << 6);      // grid (64,12), 0..767
  const int swz = (lid & 7) * 96 + (lid >> 3);         // bijective XCD chunking
  const int t0 = (swz / 12) * 128;
  const int c0 = (swz % 12) * 128;                     // 0..1535 over [Wq|Wkv] rows
  const int cls = c0 >> 9;                             // 0=q 1=k 2=v

  const int tid = threadIdx.x;
  const int wave = tid >> 6, lane = tid & 63;
  const int quad = lane >> 4, l16 = lane & 15;
  const int wm = wave >> 1, wn = wave & 1;

  // staging source: row r = i*64 + tid>>2, granule gc = (tid&3)^(r&3)
  const int r_ = tid >> 2;
  const int gc = (tid & 3) ^ (r_ & 3);
  const unsigned short* abase = xbf + (size_t)(t0 + r_) * IN_ + gc * 8;
  const unsigned short* bbase = wbf + (size_t)(c0 + r_) * IN_ + gc * 8;

  auto stage = [&](int k0, int buf) {
    unsigned short* sA = sm + buf * 8192;
    unsigned short* sB = sA + 4096;
    gld16(abase + k0,            sA + tid * 8);
    gld16(abase + 64 * IN_ + k0, sA + 2048 + tid * 8);
    gld16(bbase + k0,            sB + tid * 8);
    gld16(bbase + 64 * IN_ + k0, sB + 2048 + tid * 8);
  };

  f32x4 acc[4][4];
  #pragma unroll
  for (int i = 0; i < 4; i++)
    #pragma unroll
    for (int j = 0; j < 4; j++) acc[i][j] = (f32x4){0.f, 0.f, 0.f, 0.f};

  stage(0, 0);

  for (int kt = 0; kt < 16; kt++) {
    const int cur = kt & 1;
    __syncthreads();                       // tile kt landed; prev compute done
    if (kt + 1 < 16) stage((kt + 1) * 32, cur ^ 1);
    const unsigned short* sA = sm + cur * 8192;
    const unsigned short* sB = sA + 4096;
    const int sw = ((quad ^ (l16 & 3)) << 3);
    short8 af[4], bf[4];
    #pragma unroll
    for (int mi = 0; mi < 4; mi++)
      af[mi] = *(const short8*)&sA[(wm * 64 + mi * 16 + l16) * 32 + sw];
    #pragma unroll
    for (int ni = 0; ni < 4; ni++)
      bf[ni] = *(const short8*)&sB[(wn * 64 + ni * 16 + l16) * 32 + sw];
    #pragma unroll
    for (int mi = 0; mi < 4; mi++)
      #pragma unroll
      for (int ni = 0; ni < 4; ni++)
        acc[mi][ni] = __builtin_amdgcn_mfma_f32_16x16x32_bf16(af[mi], bf[ni], acc[mi][ni], 0, 0, 0);
  }

  __syncthreads();  // main-loop LDS reads done; reuse sm for epilogue

  if (cls < 2) {
    // token-major C tile [128 tok][136], coalesced 128B-run readback
    const float qs = (cls == 0) ? CLOG2_ : 1.0f;   // fold softmax scale into Q
    #pragma unroll
    for (int mi = 0; mi < 4; mi++) {
      const int row0 = wm * 64 + mi * 16 + quad * 4;
      #pragma unroll
      for (int ni = 0; ni < 4; ni++) {
        const int col = wn * 64 + ni * 16 + l16;
        #pragma unroll
        for (int r = 0; r < 4; r++)
          sm[(row0 + r) * 136 + col] = f2bf(acc[mi][ni][r] * qs);
      }
    }
    __syncthreads();
    const int row = tid >> 1, half = tid & 1;
    const int t = t0 + row, bb = t >> 11, nn = t & (N_ - 1);
    const int cw = (c0 & 511) + half * 64;
    const int hh = cw >> 6;
    unsigned short* dst = ((cls == 0) ? qws : kws) +
                          ((size_t)(bb * H_ + hh) * N_ + nn) * D_;
    const unsigned short* srcp = &sm[row * 136 + half * 64];
    #pragma unroll
    for (int j = 0; j < 8; j++)
      *(uint4*)(dst + j * 8) = *(const uint4*)(srcp + j * 8);
  } else {
    // transposed C tile [128 col][136 tok], coalesced readback along n
    #pragma unroll
    for (int mi = 0; mi < 4; mi++) {
      const int tk = wm * 64 + mi * 16 + quad * 4;
      #pragma unroll
      for (int ni = 0; ni < 4; ni++) {
        const int col = wn * 64 + ni * 16 + l16;
        bs4 pk4 = pack4(acc[mi][ni][0], acc[mi][ni][1], acc[mi][ni][2], acc[mi][ni][3]);
        *(bs4*)&sm[col * 136 + tk] = pk4;
      }
    }
    __syncthreads();
    const int col = tid >> 1, half = tid & 1;
    const int cw = (c0 - 1024) + col;
    const int hh = cw >> 6, dd = cw & 63;
    const int bb = t0 >> 11, n0 = (t0 & (N_ - 1)) + half * 64;
    unsigned short* dst = vws + ((size_t)(bb * H_ + hh) * D_ + dd) * N_ + n0;
    const unsigned short* srcp = &sm[col * 136 + half * 64];
    #pragma unroll
    for (int j = 0; j < 8; j++)
      *(uint4*)(dst + j * 8) = *(const uint4*)(srcp + j * 8);
  }
}

// ---------------------------------------------------------------------------
// Kernel 2: flash attention. Transposed-S, unshifted exp2 (scale pre-folded
// into Q), global_load_lds dbuf staging, 1 barrier/iter, XCD swizzle (R1),
// K=32 PV with permlane P-assembly (R2: conflicts 8.49M->98K).
// R4: LDS-BW attack. R2 was LDS-read-bound (2.1M b128 reads x 12cyc = 41us;
// every fragment read 4x-redundant across waves). New shape: 512-thr blocks
// (8 waves), q-tile 128, KEY-SPLIT: waves 0-3 own keys [0,32) of each tile,
// waves 4-7 own keys [32,64); each wave 32 q-rows (2 row-blocks).
// Per wave-iter: 4 K + 4 V reads feed 18 MFMA (2.25 MFMA/read, 2x R2).
// Grid 512 x 512thr -> 2 blocks/CU -> 16 waves/CU = 4/SIMD (same occupancy
// as R2). Unshifted exp2 => key-split partials combine ADDITIVELY: one
// f32 LDS combine at the end (swizzled slots, no 256B-stride conflict).
// ---------------------------------------------------------------------------
__global__ __launch_bounds__(512, 4) void attention_kernel(
    const unsigned short* __restrict__ qws,
    const unsigned short* __restrict__ kws,
    const unsigned short* __restrict__ vws,
    unsigned short* __restrict__ ows)
{
  __shared__ __attribute__((aligned(16))) unsigned short sm[2][8192];
  __shared__ float sml[128];   // l-partials from the key-upper half

  const int lid = blockIdx.x + (blockIdx.y << 4);      // grid (16,32), 0..511
  const int swz = ((lid & 7) << 6) + (lid >> 3);       // bijective XCD chunking
  const int q0 = (swz & 15) * 128;                     // q-tile fast within chunk
  const int bh = swz >> 4;                             // 4 contiguous bh per XCD
  const int tid = threadIdx.x;
  const int wave = tid >> 6, lane = tid & 63;
  const int quad = lane >> 4, l16 = lane & 15;
  const int rbw = wave & 3;                            // row-block pair owner
  const int kh = wave >> 2;                            // key half [0,32) / [32,64)

  const unsigned short* qbase = qws + (size_t)bh * N_ * D_;
  const unsigned short* kbase = kws + (size_t)bh * N_ * D_;
  const unsigned short* vbase = vws + (size_t)bh * D_ * N_;

  // two q row-blocks per wave: rows q0 + rbw*32 + rb*16 + l16
  short8 qf[2][2];
  #pragma unroll
  for (int rb = 0; rb < 2; rb++) {
    const int qrow = q0 + rbw * 32 + rb * 16 + l16;
    #pragma unroll
    for (int kc = 0; kc < 2; kc++)
      qf[rb][kc] = *(const short8*)(qbase + (size_t)qrow * D_ + kc * 32 + quad * 8);
  }

  f32x4 ot[2][4];
  f32x4 otl[2];
  #pragma unroll
  for (int rb = 0; rb < 2; rb++) {
    #pragma unroll
    for (int db = 0; db < 4; db++) ot[rb][db] = (f32x4){0.f, 0.f, 0.f, 0.f};
    otl[rb] = (f32x4){0.f, 0.f, 0.f, 0.f};
  }
  const short8 ones8 = {(short)0x3F80, (short)0x3F80, (short)0x3F80, (short)0x3F80,
                        (short)0x3F80, (short)0x3F80, (short)0x3F80, (short)0x3F80};

  // staging: 512 lanes x 16B = one full 8KB tile per gld16 call
  const int r_ = tid >> 3;                   // 0..63
  const int gc = (tid & 7) ^ (r_ & 7);
  const unsigned short* kst = kbase + (size_t)r_ * D_ + gc * 8;
  const unsigned short* vst = vbase + (size_t)r_ * N_ + gc * 8;

  {
    gld16(kst, &sm[0][0]    + tid * 8);
    gld16(vst, &sm[0][4096] + tid * 8);
  }

  for (int kt = 0; kt < N_ / 64; kt++) {
    const int cur = kt & 1;
    __syncthreads();
    if (kt + 1 < N_ / 64) {
      const int k0 = (kt + 1) * 64;
      gld16(kst + (size_t)k0 * D_, &sm[cur ^ 1][0]    + tid * 8);
      gld16(vst + k0,              &sm[cur ^ 1][4096] + tid * 8);
    }
    const unsigned short* Ks = &sm[cur][0];
    const unsigned short* Vs = &sm[cur][4096];

    // QK^T over this wave's 32-key half; each K fragment feeds both row-blocks
    f32x4 st[2][2];
    #pragma unroll
    for (int rb = 0; rb < 2; rb++)
      #pragma unroll
      for (int nb = 0; nb < 2; nb++) st[rb][nb] = (f32x4){0.f, 0.f, 0.f, 0.f};
    #pragma unroll
    for (int kc = 0; kc < 2; kc++) {
      const int sw = (((kc * 4 + quad) ^ (l16 & 7)) << 3);
      #pragma unroll
      for (int nb = 0; nb < 2; nb++) {
        short8 kf = *(const short8*)&Ks[(kh * 32 + nb * 16 + l16) * 64 + sw];
        st[0][nb] = __builtin_amdgcn_mfma_f32_16x16x32_bf16(kf, qf[0][kc], st[0][nb], 0, 0, 0);
        st[1][nb] = __builtin_amdgcn_mfma_f32_16x16x32_bf16(kf, qf[1][kc], st[1][nb], 0, 0, 0);
      }
    }

    // softmax numerators + K=32 P-fragment assembly (one per row-block)
    short8 pA[2];
    #pragma unroll
    for (int rb = 0; rb < 2; rb++) {
      bs4 pf[2];
      #pragma unroll
      for (int nb = 0; nb < 2; nb++) {
        float p0 = __builtin_amdgcn_exp2f(st[rb][nb][0]);
        float p1 = __builtin_amdgcn_exp2f(st[rb][nb][1]);
        float p2 = __builtin_amdgcn_exp2f(st[rb][nb][2]);
        float p3 = __builtin_amdgcn_exp2f(st[rb][nb][3]);
        pf[nb] = pack4(p0, p1, p2, p3);
      }
      pA[rb] = assemble_p(pf[0], pf[1]);
    }

    // PV over this wave's 32-key half; each V fragment feeds both row-blocks
    {
      const int slot = (((kh * 4 + quad) ^ (l16 & 7)) << 3);
      short8 vf8[4];
      #pragma unroll
      for (int db = 0; db < 4; db++)
        vf8[db] = *(const short8*)&Vs[(db * 16 + l16) * 64 + slot];
      #pragma unroll
      for (int rb = 0; rb < 2; rb++) {
        #pragma unroll
        for (int db = 0; db < 4; db++)
          ot[rb][db] = __builtin_amdgcn_mfma_f32_16x16x32_bf16(vf8[db], pA[rb], ot[rb][db], 0, 0, 0);
        otl[rb] = __builtin_amdgcn_mfma_f32_16x16x32_bf16(ones8, pA[rb], otl[rb], 0, 0, 0);
      }
    }
  }

  // ---- key-half combine (additive: no running max in unshifted exp2) ----
  __syncthreads();                         // main-loop LDS traffic done
  float* Of = (float*)sm;                  // [128 q][16 f32x4 slots], swizzled
  if (kh == 1) {
    #pragma unroll
    for (int rb = 0; rb < 2; rb++) {
      const int q = rbw * 32 + rb * 16 + l16;
      #pragma unroll
      for (int db = 0; db < 4; db++) {
        const int slot = (db * 4 + quad) ^ l16;   // break 256B-stride conflict
        *(f32x4*)&Of[q * 64 + slot * 4] = ot[rb][db];
      }
      if (quad == 0) sml[q] = otl[rb][0];  // every lane's otl[.][0] == l(q=l16)
    }
  }
  __syncthreads();
  bs4 pk[2][4];
  if (kh == 0) {
    #pragma unroll
    for (int rb = 0; rb < 2; rb++) {
      const int q = rbw * 32 + rb * 16 + l16;
      const float inv = 1.f / (otl[rb][0] + sml[q]);
      #pragma unroll
      for (int db = 0; db < 4; db++) {
        const int slot = (db * 4 + quad) ^ l16;
        f32x4 p = *(const f32x4*)&Of[q * 64 + slot * 4];
        pk[rb][db] = pack4((ot[rb][db][0] + p[0]) * inv, (ot[rb][db][1] + p[1]) * inv,
                           (ot[rb][db][2] + p[2]) * inv, (ot[rb][db][3] + p[3]) * inv);
      }
    }
  }
  __syncthreads();                         // all Of reads done; reuse as overlay
  unsigned short* Os = (unsigned short*)sm;   // 128 x 72 overlay (18 KB)
  if (kh == 0) {
    #pragma unroll
    for (int rb = 0; rb < 2; rb++)
      #pragma unroll
      for (int db = 0; db < 4; db++)
        *(bs4*)&Os[(rbw * 32 + rb * 16 + l16) * 72 + db * 16 + quad * 4] = pk[rb][db];
  }
  __syncthreads();
  // coalesced global copy: 512 threads x 32B
  const int b_ = bh >> 3, h_ = bh & 7;
  const int qloc = tid >> 2, chunk = tid & 3;
  unsigned short* dst = ows + ((size_t)b_ * N_ + q0 + qloc) * (H_ * D_) + h_ * 64 + chunk * 16;
  const unsigned short* srcp = &Os[qloc * 72 + chunk * 16];
  *(uint4*)dst = *(const uint4*)srcp;
  *(uint4*)(dst + 8) = *(const uint4*)(srcp + 8);
}

// ---------------------------------------------------------------------------
// Kernel 3: output projection. 128x64 tile, BK=32, DOUBLE-BUFFERED
// global_load_lds staging. fp32 out + bias, 64B-run stores.
// XCD-chunked block swizzle (T1, bijective: 512%8==0).
// ---------------------------------------------------------------------------
__global__ __launch_bounds__(256) void out_gemm_kernel(
    const unsigned short* __restrict__ ain, const unsigned short* __restrict__ wobf,
    const float* __restrict__ bo, float* __restrict__ y)
{
  // buf b at sm + b*6144: A 4096 | B 2048 shorts; total 12288 shorts = 24 KB
  __shared__ __attribute__((aligned(16))) unsigned short sm[12288];

  const int lid = blockIdx.x + (blockIdx.y << 6);      // grid (64,8), 0..511
  const int swz = ((lid & 7) << 6) + (lid >> 3);       // bijective XCD chunking
  const int t0 = (swz >> 3) * 128;
  const int c0 = (swz & 7) * 64;
  const int tid = threadIdx.x;
  const int wave = tid >> 6, lane = tid & 63;
  const int quad = lane >> 4, l16 = lane & 15;

  const int r_ = tid >> 2;
  const int gc = (tid & 3) ^ (r_ & 3);
  const unsigned short* abase = ain  + (size_t)(t0 + r_) * IN_ + gc * 8;
  const unsigned short* bbase = wobf + (size_t)(c0 + r_) * IN_ + gc * 8;

  auto stage = [&](int k0, int buf) {
    unsigned short* sA = sm + buf * 6144;
    unsigned short* sB = sA + 4096;
    gld16(abase + k0,            sA + tid * 8);
    gld16(abase + 64 * IN_ + k0, sA + 2048 + tid * 8);
    gld16(bbase + k0,            sB + tid * 8);     // B: 64 rows x 4 granules = 256 slots
  };

  f32x4 acc[2][4];
  #pragma unroll
  for (int i = 0; i < 2; i++)
    #pragma unroll
    for (int j = 0; j < 4; j++) acc[i][j] = (f32x4){0.f, 0.f, 0.f, 0.f};

  stage(0, 0);

  for (int kt = 0; kt < 16; kt++) {
    const int cur = kt & 1;
    __syncthreads();
    if (kt + 1 < 16) stage((kt + 1) * 32, cur ^ 1);
    const unsigned short* sA = sm + cur * 6144;
    const unsigned short* sB = sA + 4096;
    const int sw = ((quad ^ (l16 & 3)) << 3);
    short8 af[2], bf[4];
    #pragma unroll
    for (int mi = 0; mi < 2; mi++)
      af[mi] = *(const short8*)&sA[(wave * 32 + mi * 16 + l16) * 32 + sw];
    #pragma unroll
    for (int ni = 0; ni < 4; ni++)
      bf[ni] = *(const short8*)&sB[(ni * 16 + l16) * 32 + sw];
    #pragma unroll
    for (int mi = 0; mi < 2; mi++)
      #pragma unroll
      for (int ni = 0; ni < 4; ni++)
        acc[mi][ni] = __builtin_amdgcn_mfma_f32_16x16x32_bf16(af[mi], bf[ni], acc[mi][ni], 0, 0, 0);
  }

  #pragma unroll
  for (int mi = 0; mi < 2; mi++) {
    const int t = t0 + wave * 32 + mi * 16 + quad * 4;
    #pragma unroll
    for (int ni = 0; ni < 4; ni++) {
      const int c = c0 + ni * 16 + l16;
      const float bias = bo[c];
      float* dst = y + (size_t)t * IN_ + c;
      dst[0]        = acc[mi][ni][0] + bias;
      dst[IN_]      = acc[mi][ni][1] + bias;
      dst[2 * IN_]  = acc[mi][ni][2] + bias;
      dst[3 * IN_]  = acc[mi][ni][3] + bias;
    }
  }
}

extern "C" void kernel_launch(void* const* d_in, const int* in_sizes, int n_in,
                              void* d_out, int out_size, void* d_ws, size_t ws_size,
                              hipStream_t stream) {
  const float* x   = (const float*)d_in[0];
  const float* Wq  = (const float*)d_in[1];
  const float* Wkv = (const float*)d_in[2];
  const float* Wo  = (const float*)d_in[3];
  const float* bo  = (const float*)d_in[4];
  float* out = (float*)d_out;

  // ws (shorts): qws 4M | kws 4M | vws 4M | ows 4M | wbf 768K | wobf 256K  (~34 MB, proven)
  unsigned short* qws  = (unsigned short*)d_ws;
  unsigned short* kws  = qws + (size_t)TOK_ * 512;
  unsigned short* vws  = kws + (size_t)TOK_ * 512;
  unsigned short* ows  = vws + (size_t)TOK_ * 512;
  unsigned short* wbf  = ows + (size_t)TOK_ * 512;       // [Wq 512 | Wkv 1024] x 512
  unsigned short* wobf = wbf + (size_t)1536 * 512;
  unsigned short* xbf  = ows;  // alias: consumed by qkv before attention writes ows

  conv_all_kernel<<<dim3(2560), 256, 0, stream>>>(x, Wq, Wkv, Wo, xbf, wbf, wobf);
  qkv_gemm_kernel<<<dim3(TOK_ / 128, 1536 / 128), 256, 0, stream>>>(xbf, wbf, qws, kws, vws);
  attention_kernel<<<dim3(N_ / 128, B_ * H_), 512, 0, stream>>>(qws, kws, vws, ows);
  out_gemm_kernel<<<dim3(TOK_ / 128, 512 / 64), 256, 0, stream>>>(ows, wobf, bo, out);
}

// Round 5
// 151.992 us; speedup vs baseline: 1.1429x; 1.0028x over previous
//
#include <hip/hip_runtime.h>
#include <hip/hip_bf16.h>

#define H_ 8
#define D_ 64
#define IN_ 512
#define B_ 4
#define N_ 2048
#define TOK_ (B_*N_)
// softmax in exp2 domain: scale * log2(e) (folded into Q at projection time)
#define CLOG2_ 0.18033688011112042f

typedef __attribute__((ext_vector_type(8))) short short8;
typedef __attribute__((ext_vector_type(4))) short bs4;
typedef __attribute__((ext_vector_type(4))) float f32x4;

__device__ __forceinline__ unsigned short f2bf(float f) {
  unsigned int u = __float_as_uint(f);
  u += 0x7FFFu + ((u >> 16) & 1u);
  return (unsigned short)(u >> 16);
}

// packed converts: v_cvt_pk_bf16_f32
__device__ __forceinline__ short8 cvt8(const float4 a, const float4 b) {
  union { short8 v; __hip_bfloat162 h[4]; } z;
  z.h[0] = __float22bfloat162_rn(make_float2(a.x, a.y));
  z.h[1] = __float22bfloat162_rn(make_float2(a.z, a.w));
  z.h[2] = __float22bfloat162_rn(make_float2(b.x, b.y));
  z.h[3] = __float22bfloat162_rn(make_float2(b.z, b.w));
  return z.v;
}

__device__ __forceinline__ bs4 pack4(float a, float b, float c, float d) {
  union { bs4 v; __hip_bfloat162 h[2]; } z;
  z.h[0] = __float22bfloat162_rn(make_float2(a, b));
  z.h[1] = __float22bfloat162_rn(make_float2(c, d));
  return z.v;
}

// Reassemble two K=16 P-fragments (keys nb*16+quad*4+r layout) into one K=32
// B-fragment (keys quad*8+j layout) with 4 lane-swaps.
__device__ __forceinline__ short8 assemble_p(bs4 pa, bs4 pb) {
  union { bs4 v; unsigned int w[2]; } A, B;
  A.v = pa; B.v = pb;
  auto s0 = __builtin_amdgcn_permlane32_swap(A.w[0], B.w[0], false, false);
  auto s1 = __builtin_amdgcn_permlane32_swap(A.w[1], B.w[1], false, false);
  auto t0 = __builtin_amdgcn_permlane16_swap(s0[0], s0[1], false, false);
  auto t1 = __builtin_amdgcn_permlane16_swap(s1[0], s1[1], false, false);
  union { short8 v; unsigned int w[4]; } R;
  R.w[0] = t0[0];   // j=0,1
  R.w[1] = t1[0];   // j=2,3
  R.w[2] = t0[1];   // j=4,5
  R.w[3] = t1[1];   // j=6,7
  return R.v;
}

// async global->LDS, 16B per lane; dest = wave-uniform base + lane*16
__device__ __forceinline__ void gld16(const unsigned short* g, unsigned short* l) {
  __builtin_amdgcn_global_load_lds(
      (const __attribute__((address_space(1))) void*)g,
      (__attribute__((address_space(3))) void*)l, 16, 0, 0);
}

// ---------------------------------------------------------------------------
// Kernel 0: merged fp32 -> bf16 convert (x, Wq, Wkv, Wo) in ONE launch.
// ---------------------------------------------------------------------------
__global__ __launch_bounds__(256) void conv_all_kernel(
    const float* __restrict__ x, const float* __restrict__ Wq,
    const float* __restrict__ Wkv, const float* __restrict__ Wo,
    unsigned short* __restrict__ xbf, unsigned short* __restrict__ wbf,
    unsigned short* __restrict__ wobf)
{
  const int b = blockIdx.x;
  const float* src;
  unsigned short* dst;
  size_t base;
  if (b < 2048)      { src = x;   dst = xbf;             base = (size_t)b * 2048; }
  else if (b < 2176) { src = Wq;  dst = wbf;             base = (size_t)(b - 2048) * 2048; }
  else if (b < 2432) { src = Wkv; dst = wbf + 512 * 512; base = (size_t)(b - 2176) * 2048; }
  else               { src = Wo;  dst = wobf;            base = (size_t)(b - 2432) * 2048; }
  size_t i = base + (size_t)threadIdx.x * 8;
  float4 a = *(const float4*)(src + i);
  float4 c = *(const float4*)(src + i + 4);
  *(short8*)(dst + i) = cvt8(a, c);
}

// ---------------------------------------------------------------------------
// Kernel 1: QKV projection. 128x128 tile, BK=32, DOUBLE-BUFFERED
// global_load_lds staging, source-permuted XOR swizzle.
// Q pre-scaled by CLOG2_. Q,K -> [b,h,n,d]; V -> [b,h,d,n]. LDS epilogues.
// XCD-chunked block swizzle (T1, bijective: 768%8==0).
// ---------------------------------------------------------------------------
__global__ __launch_bounds__(256) void qkv_gemm_kernel(
    const unsigned short* __restrict__ xbf, const unsigned short* __restrict__ wbf,
    unsigned short* __restrict__ qws, unsigned short* __restrict__ kws,
    unsigned short* __restrict__ vws)
{
  // staging: buf b at sm + b*8192 (A 4096 | B 4096 shorts); epilogue overlay 128*136
  __shared__ __attribute__((aligned(16))) unsigned short sm[128 * 136];

  const int lid = blockIdx.x + (blockIdx.y << 6);      // grid (64,12), 0..767
  const int swz = (lid & 7) * 96 + (lid >> 3);         // bijective XCD chunking
  const int t0 = (swz / 12) * 128;
  const int c0 = (swz % 12) * 128;                     // 0..1535 over [Wq|Wkv] rows
  const int cls = c0 >> 9;                             // 0=q 1=k 2=v

  const int tid = threadIdx.x;
  const int wave = tid >> 6, lane = tid & 63;
  const int quad = lane >> 4, l16 = lane & 15;
  const int wm = wave >> 1, wn = wave & 1;

  // staging source: row r = i*64 + tid>>2, granule gc = (tid&3)^(r&3)
  const int r_ = tid >> 2;
  const int gc = (tid & 3) ^ (r_ & 3);
  const unsigned short* abase = xbf + (size_t)(t0 + r_) * IN_ + gc * 8;
  const unsigned short* bbase = wbf + (size_t)(c0 + r_) * IN_ + gc * 8;

  auto stage = [&](int k0, int buf) {
    unsigned short* sA = sm + buf * 8192;
    unsigned short* sB = sA + 4096;
    gld16(abase + k0,            sA + tid * 8);
    gld16(abase + 64 * IN_ + k0, sA + 2048 + tid * 8);
    gld16(bbase + k0,            sB + tid * 8);
    gld16(bbase + 64 * IN_ + k0, sB + 2048 + tid * 8);
  };

  f32x4 acc[4][4];
  #pragma unroll
  for (int i = 0; i < 4; i++)
    #pragma unroll
    for (int j = 0; j < 4; j++) acc[i][j] = (f32x4){0.f, 0.f, 0.f, 0.f};

  stage(0, 0);

  for (int kt = 0; kt < 16; kt++) {
    const int cur = kt & 1;
    __syncthreads();                       // tile kt landed; prev compute done
    if (kt + 1 < 16) stage((kt + 1) * 32, cur ^ 1);
    const unsigned short* sA = sm + cur * 8192;
    const unsigned short* sB = sA + 4096;
    const int sw = ((quad ^ (l16 & 3)) << 3);
    short8 af[4], bf[4];
    #pragma unroll
    for (int mi = 0; mi < 4; mi++)
      af[mi] = *(const short8*)&sA[(wm * 64 + mi * 16 + l16) * 32 + sw];
    #pragma unroll
    for (int ni = 0; ni < 4; ni++)
      bf[ni] = *(const short8*)&sB[(wn * 64 + ni * 16 + l16) * 32 + sw];
    #pragma unroll
    for (int mi = 0; mi < 4; mi++)
      #pragma unroll
      for (int ni = 0; ni < 4; ni++)
        acc[mi][ni] = __builtin_amdgcn_mfma_f32_16x16x32_bf16(af[mi], bf[ni], acc[mi][ni], 0, 0, 0);
  }

  __syncthreads();  // main-loop LDS reads done; reuse sm for epilogue

  if (cls < 2) {
    // token-major C tile [128 tok][136], coalesced 128B-run readback
    const float qs = (cls == 0) ? CLOG2_ : 1.0f;   // fold softmax scale into Q
    #pragma unroll
    for (int mi = 0; mi < 4; mi++) {
      const int row0 = wm * 64 + mi * 16 + quad * 4;
      #pragma unroll
      for (int ni = 0; ni < 4; ni++) {
        const int col = wn * 64 + ni * 16 + l16;
        #pragma unroll
        for (int r = 0; r < 4; r++)
          sm[(row0 + r) * 136 + col] = f2bf(acc[mi][ni][r] * qs);
      }
    }
    __syncthreads();
    const int row = tid >> 1, half = tid & 1;
    const int t = t0 + row, bb = t >> 11, nn = t & (N_ - 1);
    const int cw = (c0 & 511) + half * 64;
    const int hh = cw >> 6;
    unsigned short* dst = ((cls == 0) ? qws : kws) +
                          ((size_t)(bb * H_ + hh) * N_ + nn) * D_;
    const unsigned short* srcp = &sm[row * 136 + half * 64];
    #pragma unroll
    for (int j = 0; j < 8; j++)
      *(uint4*)(dst + j * 8) = *(const uint4*)(srcp + j * 8);
  } else {
    // transposed C tile [128 col][136 tok], coalesced readback along n
    #pragma unroll
    for (int mi = 0; mi < 4; mi++) {
      const int tk = wm * 64 + mi * 16 + quad * 4;
      #pragma unroll
      for (int ni = 0; ni < 4; ni++) {
        const int col = wn * 64 + ni * 16 + l16;
        bs4 pk4 = pack4(acc[mi][ni][0], acc[mi][ni][1], acc[mi][ni][2], acc[mi][ni][3]);
        *(bs4*)&sm[col * 136 + tk] = pk4;
      }
    }
    __syncthreads();
    const int col = tid >> 1, half = tid & 1;
    const int cw = (c0 - 1024) + col;
    const int hh = cw >> 6, dd = cw & 63;
    const int bb = t0 >> 11, n0 = (t0 & (N_ - 1)) + half * 64;
    unsigned short* dst = vws + ((size_t)(bb * H_ + hh) * D_ + dd) * N_ + n0;
    const unsigned short* srcp = &sm[col * 136 + half * 64];
    #pragma unroll
    for (int j = 0; j < 8; j++)
      *(uint4*)(dst + j * 8) = *(const uint4*)(srcp + j * 8);
  }
}

// ---------------------------------------------------------------------------
// Kernel 2: flash attention. Transposed-S, unshifted exp2 (scale pre-folded
// into Q), XCD swizzle (R1), K=32 PV + permlane P-assembly (R2), 512-thr
// key-split blocks (R4: 2.25 MFMA per LDS read, 47us).
// R5: T4 counted-vmcnt pipeline. The per-iter __syncthreads forced a
// vmcnt(0) drain -> all 16 waves/CU stalled on staging loads every tile.
// Now: 3 staging buffers, prefetch 2 tiles ahead, `s_waitcnt vmcnt(2)` +
// raw s_barrier (vmcnt(0) only on the last iter). Loads get a full
// iteration (~400+ cyc) to land. WAR-safe: buffer (kt+2)%3 was read at
// iter kt-1; all its ds_reads retired before their consuming MFMAs, i.e.
// before the iter-kt barrier.
// ---------------------------------------------------------------------------
__global__ __launch_bounds__(512, 4) void attention_kernel(
    const unsigned short* __restrict__ qws,
    const unsigned short* __restrict__ kws,
    const unsigned short* __restrict__ vws,
    unsigned short* __restrict__ ows)
{
  __shared__ __attribute__((aligned(16))) unsigned short sm[3][8192];  // 48 KB
  __shared__ float sml[128];   // l-partials from the key-upper half

  const int lid = blockIdx.x + (blockIdx.y << 4);      // grid (16,32), 0..511
  const int swz = ((lid & 7) << 6) + (lid >> 3);       // bijective XCD chunking
  const int q0 = (swz & 15) * 128;                     // q-tile fast within chunk
  const int bh = swz >> 4;                             // 4 contiguous bh per XCD
  const int tid = threadIdx.x;
  const int wave = tid >> 6, lane = tid & 63;
  const int quad = lane >> 4, l16 = lane & 15;
  const int rbw = wave & 3;                            // row-block pair owner
  const int kh = wave >> 2;                            // key half [0,32) / [32,64)

  const unsigned short* qbase = qws + (size_t)bh * N_ * D_;
  const unsigned short* kbase = kws + (size_t)bh * N_ * D_;
  const unsigned short* vbase = vws + (size_t)bh * D_ * N_;

  // two q row-blocks per wave: rows q0 + rbw*32 + rb*16 + l16
  short8 qf[2][2];
  #pragma unroll
  for (int rb = 0; rb < 2; rb++) {
    const int qrow = q0 + rbw * 32 + rb * 16 + l16;
    #pragma unroll
    for (int kc = 0; kc < 2; kc++)
      qf[rb][kc] = *(const short8*)(qbase + (size_t)qrow * D_ + kc * 32 + quad * 8);
  }

  f32x4 ot[2][4];
  f32x4 otl[2];
  #pragma unroll
  for (int rb = 0; rb < 2; rb++) {
    #pragma unroll
    for (int db = 0; db < 4; db++) ot[rb][db] = (f32x4){0.f, 0.f, 0.f, 0.f};
    otl[rb] = (f32x4){0.f, 0.f, 0.f, 0.f};
  }
  const short8 ones8 = {(short)0x3F80, (short)0x3F80, (short)0x3F80, (short)0x3F80,
                        (short)0x3F80, (short)0x3F80, (short)0x3F80, (short)0x3F80};

  // staging: 512 lanes x 16B = one full 8KB tile per gld16 call
  const int r_ = tid >> 3;                   // 0..63
  const int gc = (tid & 7) ^ (r_ & 7);
  const unsigned short* kst = kbase + (size_t)r_ * D_ + gc * 8;
  const unsigned short* vst = vbase + (size_t)r_ * N_ + gc * 8;

  auto stage = [&](int kt, int buf) {
    const int k0 = kt * 64;
    gld16(kst + (size_t)k0 * D_, &sm[buf][0]    + tid * 8);
    gld16(vst + k0,              &sm[buf][4096] + tid * 8);
  };

  const int NT = N_ / 64;   // 32
  stage(0, 0);
  stage(1, 1);

  for (int kt = 0; kt < NT; kt++) {
    // tile kt's 2 loads are the oldest outstanding; allow tile kt+1's to fly
    if (kt < NT - 1) asm volatile("s_waitcnt vmcnt(2)" ::: "memory");
    else             asm volatile("s_waitcnt vmcnt(0)" ::: "memory");
    __builtin_amdgcn_s_barrier();
    if (kt + 2 < NT) stage(kt + 2, (kt + 2) % 3);

    const unsigned short* Ks = &sm[kt % 3][0];
    const unsigned short* Vs = &sm[kt % 3][4096];

    // QK^T over this wave's 32-key half; each K fragment feeds both row-blocks
    f32x4 st[2][2];
    #pragma unroll
    for (int rb = 0; rb < 2; rb++)
      #pragma unroll
      for (int nb = 0; nb < 2; nb++) st[rb][nb] = (f32x4){0.f, 0.f, 0.f, 0.f};
    #pragma unroll
    for (int kc = 0; kc < 2; kc++) {
      const int sw = (((kc * 4 + quad) ^ (l16 & 7)) << 3);
      #pragma unroll
      for (int nb = 0; nb < 2; nb++) {
        short8 kf = *(const short8*)&Ks[(kh * 32 + nb * 16 + l16) * 64 + sw];
        st[0][nb] = __builtin_amdgcn_mfma_f32_16x16x32_bf16(kf, qf[0][kc], st[0][nb], 0, 0, 0);
        st[1][nb] = __builtin_amdgcn_mfma_f32_16x16x32_bf16(kf, qf[1][kc], st[1][nb], 0, 0, 0);
      }
    }

    // softmax numerators + K=32 P-fragment assembly (one per row-block)
    short8 pA[2];
    #pragma unroll
    for (int rb = 0; rb < 2; rb++) {
      bs4 pf[2];
      #pragma unroll
      for (int nb = 0; nb < 2; nb++) {
        float p0 = __builtin_amdgcn_exp2f(st[rb][nb][0]);
        float p1 = __builtin_amdgcn_exp2f(st[rb][nb][1]);
        float p2 = __builtin_amdgcn_exp2f(st[rb][nb][2]);
        float p3 = __builtin_amdgcn_exp2f(st[rb][nb][3]);
        pf[nb] = pack4(p0, p1, p2, p3);
      }
      pA[rb] = assemble_p(pf[0], pf[1]);
    }

    // PV over this wave's 32-key half; each V fragment feeds both row-blocks
    {
      const int slot = (((kh * 4 + quad) ^ (l16 & 7)) << 3);
      short8 vf8[4];
      #pragma unroll
      for (int db = 0; db < 4; db++)
        vf8[db] = *(const short8*)&Vs[(db * 16 + l16) * 64 + slot];
      #pragma unroll
      for (int rb = 0; rb < 2; rb++) {
        #pragma unroll
        for (int db = 0; db < 4; db++)
          ot[rb][db] = __builtin_amdgcn_mfma_f32_16x16x32_bf16(vf8[db], pA[rb], ot[rb][db], 0, 0, 0);
        otl[rb] = __builtin_amdgcn_mfma_f32_16x16x32_bf16(ones8, pA[rb], otl[rb], 0, 0, 0);
      }
    }
  }

  // ---- key-half combine (additive: no running max in unshifted exp2) ----
  __syncthreads();                         // full drain; reuse sm as overlay
  float* Of = (float*)sm;                  // [128 q][16 f32x4 slots], swizzled
  if (kh == 1) {
    #pragma unroll
    for (int rb = 0; rb < 2; rb++) {
      const int q = rbw * 32 + rb * 16 + l16;
      #pragma unroll
      for (int db = 0; db < 4; db++) {
        const int slot = (db * 4 + quad) ^ l16;   // break 256B-stride conflict
        *(f32x4*)&Of[q * 64 + slot * 4] = ot[rb][db];
      }
      if (quad == 0) sml[q] = otl[rb][0];  // every lane's otl[.][0] == l(q=l16)
    }
  }
  __syncthreads();
  bs4 pk[2][4];
  if (kh == 0) {
    #pragma unroll
    for (int rb = 0; rb < 2; rb++) {
      const int q = rbw * 32 + rb * 16 + l16;
      const float inv = 1.f / (otl[rb][0] + sml[q]);
      #pragma unroll
      for (int db = 0; db < 4; db++) {
        const int slot = (db * 4 + quad) ^ l16;
        f32x4 p = *(const f32x4*)&Of[q * 64 + slot * 4];
        pk[rb][db] = pack4((ot[rb][db][0] + p[0]) * inv, (ot[rb][db][1] + p[1]) * inv,
                           (ot[rb][db][2] + p[2]) * inv, (ot[rb][db][3] + p[3]) * inv);
      }
    }
  }
  __syncthreads();                         // all Of reads done; reuse as overlay
  unsigned short* Os = (unsigned short*)sm;   // 128 x 72 overlay (18 KB)
  if (kh == 0) {
    #pragma unroll
    for (int rb = 0; rb < 2; rb++)
      #pragma unroll
      for (int db = 0; db < 4; db++)
        *(bs4*)&Os[(rbw * 32 + rb * 16 + l16) * 72 + db * 16 + quad * 4] = pk[rb][db];
  }
  __syncthreads();
  // coalesced global copy: 512 threads x 32B
  const int b_ = bh >> 3, h_ = bh & 7;
  const int qloc = tid >> 2, chunk = tid & 3;
  unsigned short* dst = ows + ((size_t)b_ * N_ + q0 + qloc) * (H_ * D_) + h_ * 64 + chunk * 16;
  const unsigned short* srcp = &Os[qloc * 72 + chunk * 16];
  *(uint4*)dst = *(const uint4*)srcp;
  *(uint4*)(dst + 8) = *(const uint4*)(srcp + 8);
}

// ---------------------------------------------------------------------------
// Kernel 3: output projection. 128x64 tile, BK=32, DOUBLE-BUFFERED
// global_load_lds staging. fp32 out + bias, 64B-run stores.
// XCD-chunked block swizzle (T1, bijective: 512%8==0).
// ---------------------------------------------------------------------------
__global__ __launch_bounds__(256) void out_gemm_kernel(
    const unsigned short* __restrict__ ain, const unsigned short* __restrict__ wobf,
    const float* __restrict__ bo, float* __restrict__ y)
{
  // buf b at sm + b*6144: A 4096 | B 2048 shorts; total 12288 shorts = 24 KB
  __shared__ __attribute__((aligned(16))) unsigned short sm[12288];

  const int lid = blockIdx.x + (blockIdx.y << 6);      // grid (64,8), 0..511
  const int swz = ((lid & 7) << 6) + (lid >> 3);       // bijective XCD chunking
  const int t0 = (swz >> 3) * 128;
  const int c0 = (swz & 7) * 64;
  const int tid = threadIdx.x;
  const int wave = tid >> 6, lane = tid & 63;
  const int quad = lane >> 4, l16 = lane & 15;

  const int r_ = tid >> 2;
  const int gc = (tid & 3) ^ (r_ & 3);
  const unsigned short* abase = ain  + (size_t)(t0 + r_) * IN_ + gc * 8;
  const unsigned short* bbase = wobf + (size_t)(c0 + r_) * IN_ + gc * 8;

  auto stage = [&](int k0, int buf) {
    unsigned short* sA = sm + buf * 6144;
    unsigned short* sB = sA + 4096;
    gld16(abase + k0,            sA + tid * 8);
    gld16(abase + 64 * IN_ + k0, sA + 2048 + tid * 8);
    gld16(bbase + k0,            sB + tid * 8);     // B: 64 rows x 4 granules = 256 slots
  };

  f32x4 acc[2][4];
  #pragma unroll
  for (int i = 0; i < 2; i++)
    #pragma unroll
    for (int j = 0; j < 4; j++) acc[i][j] = (f32x4){0.f, 0.f, 0.f, 0.f};

  stage(0, 0);

  for (int kt = 0; kt < 16; kt++) {
    const int cur = kt & 1;
    __syncthreads();
    if (kt + 1 < 16) stage((kt + 1) * 32, cur ^ 1);
    const unsigned short* sA = sm + cur * 6144;
    const unsigned short* sB = sA + 4096;
    const int sw = ((quad ^ (l16 & 3)) << 3);
    short8 af[2], bf[4];
    #pragma unroll
    for (int mi = 0; mi < 2; mi++)
      af[mi] = *(const short8*)&sA[(wave * 32 + mi * 16 + l16) * 32 + sw];
    #pragma unroll
    for (int ni = 0; ni < 4; ni++)
      bf[ni] = *(const short8*)&sB[(ni * 16 + l16) * 32 + sw];
    #pragma unroll
    for (int mi = 0; mi < 2; mi++)
      #pragma unroll
      for (int ni = 0; ni < 4; ni++)
        acc[mi][ni] = __builtin_amdgcn_mfma_f32_16x16x32_bf16(af[mi], bf[ni], acc[mi][ni], 0, 0, 0);
  }

  #pragma unroll
  for (int mi = 0; mi < 2; mi++) {
    const int t = t0 + wave * 32 + mi * 16 + quad * 4;
    #pragma unroll
    for (int ni = 0; ni < 4; ni++) {
      const int c = c0 + ni * 16 + l16;
      const float bias = bo[c];
      float* dst = y + (size_t)t * IN_ + c;
      dst[0]        = acc[mi][ni][0] + bias;
      dst[IN_]      = acc[mi][ni][1] + bias;
      dst[2 * IN_]  = acc[mi][ni][2] + bias;
      dst[3 * IN_]  = acc[mi][ni][3] + bias;
    }
  }
}

extern "C" void kernel_launch(void* const* d_in, const int* in_sizes, int n_in,
                              void* d_out, int out_size, void* d_ws, size_t ws_size,
                              hipStream_t stream) {
  const float* x   = (const float*)d_in[0];
  const float* Wq  = (const float*)d_in[1];
  const float* Wkv = (const float*)d_in[2];
  const float* Wo  = (const float*)d_in[3];
  const float* bo  = (const float*)d_in[4];
  float* out = (float*)d_out;

  // ws (shorts): qws 4M | kws 4M | vws 4M | ows 4M | wbf 768K | wobf 256K  (~34 MB, proven)
  unsigned short* qws  = (unsigned short*)d_ws;
  unsigned short* kws  = qws + (size_t)TOK_ * 512;
  unsigned short* vws  = kws + (size_t)TOK_ * 512;
  unsigned short* ows  = vws + (size_t)TOK_ * 512;
  unsigned short* wbf  = ows + (size_t)TOK_ * 512;       // [Wq 512 | Wkv 1024] x 512
  unsigned short* wobf = wbf + (size_t)1536 * 512;
  unsigned short* xbf  = ows;  // alias: consumed by qkv before attention writes ows

  conv_all_kernel<<<dim3(2560), 256, 0, stream>>>(x, Wq, Wkv, Wo, xbf, wbf, wobf);
  qkv_gemm_kernel<<<dim3(TOK_ / 128, 1536 / 128), 256, 0, stream>>>(xbf, wbf, qws, kws, vws);
  attention_kernel<<<dim3(N_ / 128, B_ * H_), 512, 0, stream>>>(qws, kws, vws, ows);
  out_gemm_kernel<<<dim3(TOK_ / 128, 512 / 64), 256, 0, stream>>>(ows, wobf, bo, out);
}